// Round 8
// baseline (1732.784 us; speedup 1.0000x reference)
//
#include <hip/hip_runtime.h>

constexpr int N = 4;
constexpr int C = 64;
constexpr int H = 256;
constexpr int W = 448;
constexpr int HW = H * W;

// 16x4 bins (one wave owns one bin; 64 px)
constexpr int BSX = 16;
constexpr int BSY = 4;
constexpr int BW_ = W / BSX;           // 28
constexpr int BH_ = H / BSY;           // 64
constexpr int BINS_PB = BW_ * BH_;     // 1792 per batch
constexpr int BINS = N * BINS_PB;      // 7168

// ===================== GATHER PATH (R8) =====================================
// R7 post-mortem: gather4 361us, VALUBusy 34.6%, Occupancy 17.3%. Two issues:
// (a) 4-wave blocks -> coarse balance, occupancy well under the 50% VGPR cap;
// (b) pipeline 1-deep on a 2-load chain (record -> row addr -> row load):
//     record wait lands mid-iter, row gets <1 iter of cover vs ~500cyc LLC.
// Also 32/64 fmacs multiply a provably-zero row weight, and the norm pass
// re-walks records serially.
// R8: 1-wave blocks (grid=BINS, launch_bounds(64,4) -> 16 blocks/CU);
// records prefetched 3-ahead, rows 2-ahead (both get ~2 iters of cover);
// wave-uniform switch on floor(fyl) -> only the <=2 live rows (32 fmacs);
// norm fused into the main loop (lane = channel for acc, pixel for nrm).

__device__ __forceinline__ int binsOf(int x0, int y0, int bins[4]) {
    const int x1 = x0 + 1, y1 = y0 + 1;
    int n = 0;
    int bxA = -2, bxB = -2, byA = -2, byB = -2;
    if ((unsigned)x0 < (unsigned)W) bxA = x0 >> 4;
    if ((unsigned)x1 < (unsigned)W) { const int t = x1 >> 4; if (t != bxA) bxB = t; }
    if ((unsigned)y0 < (unsigned)H) byA = y0 >> 2;
    if ((unsigned)y1 < (unsigned)H) { const int t = y1 >> 2; if (t != byA) byB = t; }
    if (byA >= 0) {
        if (bxA >= 0) bins[n++] = byA * BW_ + bxA;
        if (bxB >= 0) bins[n++] = byA * BW_ + bxB;
    }
    if (byB >= 0) {
        if (bxA >= 0) bins[n++] = byB * BW_ + bxA;
        if (bxB >= 0) bins[n++] = byB * BW_ + bxB;
    }
    return n;
}

// count: flow-only pass, LDS-aggregated per-batch bin counts.
__global__ __launch_bounds__(1024) void count_kernel(
    const float* __restrict__ flow,
    unsigned* __restrict__ counts)    // [BINS]
{
    __shared__ unsigned lcnt[BINS_PB];
    const int tid = threadIdx.x;
    const int idx = blockIdx.x * 1024 + tid;     // HW % 1024 == 0
    const int b = idx / HW;
    const int p = idx - b * HW;
    const int y = p / W;
    const int x = p - y * W;

    for (int i = tid; i < BINS_PB; i += 1024) lcnt[i] = 0;
    __syncthreads();

    const float fx = (float)x + flow[(b * 2 + 0) * HW + p];
    const float fy = (float)y + flow[(b * 2 + 1) * HW + p];
    const int x0 = (int)floorf(fx), y0 = (int)floorf(fy);

    int bn[4];
    const int nb = binsOf(x0, y0, bn);
    for (int i = 0; i < nb; ++i) atomicAdd(&lcnt[bn[i]], 1u);
    __syncthreads();

    for (int i = tid; i < BINS_PB; i += 1024)
        if (lcnt[i]) atomicAdd(&counts[b * BINS_PB + i], lcnt[i]);
}

// scan: exclusive prefix sum of 7168 counts (= 1024*7), clamped at capE.
__global__ __launch_bounds__(1024) void scan_kernel(
    const unsigned* __restrict__ counts,
    unsigned* __restrict__ segstart,  // [BINS+1]
    unsigned capE)
{
    __shared__ unsigned lsum[1024];
    const int tid = threadIdx.x;
    unsigned v[7];
    unsigned s = 0;
#pragma unroll
    for (int i = 0; i < 7; ++i) { v[i] = counts[tid * 7 + i]; s += v[i]; }
    lsum[tid] = s;
    __syncthreads();
    for (int off = 1; off < 1024; off <<= 1) {
        const unsigned t = (tid >= off) ? lsum[tid - off] : 0u;
        __syncthreads();
        lsum[tid] += t;
        __syncthreads();
    }
    unsigned run = lsum[tid] - s;
#pragma unroll
    for (int i = 0; i < 7; ++i) {
        segstart[tid * 7 + i] = run < capE ? run : capE;
        run += v[i];
    }
    if (tid == 1023) segstart[BINS] = run < capE ? run : capE;
}

// fill2: all 1024 threads active; one source each; write 16-B records
// {fx,fy,m,bitcast(p)} via direct per-bin cursor atomics (~85 RMW/addr
// spread over the whole kernel -> negligible contention).
__global__ __launch_bounds__(1024) void fill2_kernel(
    const float* __restrict__ flow,
    const float* __restrict__ metric,
    const unsigned* __restrict__ segstart,
    unsigned* __restrict__ cursor,    // [BINS], pre-zeroed
    float4* __restrict__ recs,        // [capE]
    unsigned capE)
{
    const int tid = threadIdx.x;
    const int idx = blockIdx.x * 1024 + tid;     // HW % 1024 == 0
    const int b = idx / HW;
    const int p = idx - b * HW;
    const int y = p / W;
    const int x = p - y * W;

    const float fx = (float)x + flow[(b * 2 + 0) * HW + p];
    const float fy = (float)y + flow[(b * 2 + 1) * HW + p];
    const float m  = __expf(metric[b * HW + p]);
    const int x0 = (int)floorf(fx), y0 = (int)floorf(fy);

    int bn[4];
    const int nb = binsOf(x0, y0, bn);
    const float4 rec = make_float4(fx, fy, m, __int_as_float(p));
    const int tb = b * BINS_PB;
    for (int i = 0; i < nb; ++i) {
        const unsigned off = atomicAdd(&cursor[tb + bn[i]], 1u);
        const unsigned slot = segstart[tb + bn[i]] + off;
        if (slot < capE) recs[slot] = rec;
    }
}

// augT: pure streaming NCHW -> NHWC transpose, premultiplied by m.
__global__ __launch_bounds__(256) void augT_kernel(
    const float* __restrict__ input,
    const float* __restrict__ metric,
    float* __restrict__ aug)          // [N*HW][64]
{
    __shared__ float s_val[128][65];
    __shared__ float s_m[128];

    const int tid = threadIdx.x;
    const int blockPix = blockIdx.x * 128;       // HW % 128 == 0
    const int b = blockPix / HW;
    const int pb = blockPix - b * HW;

    if (tid < 128)
        s_m[tid] = __expf(metric[b * HW + pb + tid]);

    {
        const int sp = tid & 127;
        const int sc = tid >> 7;
        const float* ib = input + (size_t)b * C * HW + pb + sp;
#pragma unroll
        for (int c = 0; c < 32; ++c) {
            const int ch = 2 * c + sc;
            s_val[sp][ch] = ib[(size_t)ch * HW];
        }
    }
    __syncthreads();

    const int wv = tid >> 6, ln = tid & 63;
    float* abase = aug + ((size_t)b * HW + pb) * 64;
#pragma unroll
    for (int it = 0; it < 32; ++it) {
        const int j = (wv << 5) + it;
        abase[(size_t)j * 64 + ln] = s_val[j][ln] * s_m[j];
    }
}

// Static-index row accumulate (J must be a literal at each call site).
#define ROW(J, WGT) do { const float tv_ = v0 * (WGT);                    \
    _Pragma("unroll")                                                     \
    for (int i_ = 0; i_ < 16; ++i_)                                       \
        acc[(J) * 16 + i_] = fmaf(tv_, axx[i_], acc[(J) * 16 + i_]);      \
} while (0)

// gather5: grid = BINS blocks x 64 threads (1 wave = 1 bin).
// lane = CHANNEL; acc[64] = pixels (static index). Records 3-ahead, rows
// 2-ahead. Wave-uniform switch on floor(fyl) -> only live rows. Norm fused:
// lane also acts as pixel (l>>4, l&15) for the nrm scalar.
__global__ __launch_bounds__(64, 4) void gather5(
    const float4* __restrict__ recs,
    const float* __restrict__ aug,
    const unsigned* __restrict__ segstart,
    float* __restrict__ out)
{
    __shared__ float st[16][65];      // 4.2 KB
    __shared__ float s_inv[64];

    const int lane = threadIdx.x;

    // XCD-contiguous swizzle (grid 7168 % 8 == 0)
    const int nwg = gridDim.x;
    const int bid = blockIdx.x;
    const int g   = (bid & 7) * (nwg >> 3) + (bid >> 3);

    const int b   = g / BINS_PB;
    const int bin = g - b * BINS_PB;
    const int by  = bin / BW_;
    const int bx  = bin - by * BW_;
    const int qx0 = bx * BSX;
    const int qy0 = by * BSY;

    // norm identity for this lane (lane as pixel)
    const int pxx = lane & 15, pyy = lane >> 4;
    const float Xp = (float)(qx0 + pxx);
    const float Yp = (float)(qy0 + pyy);

    float acc[64];
#pragma unroll
    for (int i = 0; i < 64; ++i) acc[i] = 0.0f;
    float nrm = 0.0f;

    const int start = (int)segstart[g];
    const int end   = (int)segstart[g + 1];
    const float* ab = aug + (size_t)b * HW * 64;

    const float4 Z = make_float4(0.0f, 0.0f, 0.0f, __int_as_float(0));
    float4 r0 = Z, r1 = Z, r2 = Z;
    float v0 = 0.0f, v1 = 0.0f;
    if (start + 0 < end) r0 = recs[start + 0];
    if (start + 1 < end) r1 = recs[start + 1];
    if (start + 2 < end) r2 = recs[start + 2];
    if (start + 0 < end) {
        const int p0 = __builtin_amdgcn_readfirstlane(__float_as_int(r0.w));
        v0 = ab[(size_t)p0 * 64 + lane];
    }
    if (start + 1 < end) {
        const int p1 = __builtin_amdgcn_readfirstlane(__float_as_int(r1.w));
        v1 = ab[(size_t)p1 * 64 + lane];
    }

    for (int e = start; e < end; ++e) {
        // keep records 3 ahead, rows 2 ahead
        float4 r3 = Z;
        if (e + 3 < end) r3 = recs[e + 3];
        float v2 = 0.0f;
        if (e + 2 < end) {
            const int p2 = __builtin_amdgcn_readfirstlane(__float_as_int(r2.w));
            v2 = ab[(size_t)p2 * 64 + lane];
        }

        // ---- compute with r0, v0 ----
        const float fxl = r0.x - (float)qx0;
        const float fyl = r0.y - (float)qy0;
        float axx[16];
#pragma unroll
        for (int i = 0; i < 16; ++i)
            axx[i] = fmaxf(1.0f - fabsf(fxl - (float)i), 0.0f);

        const float fyf = floorf(fyl);
        const int   j0  = (int)fyf;        // wave-uniform, in [-1, 3]
        const float fr  = fyl - fyf;
        const float wA  = 1.0f - fr, wB = fr;
        switch (j0) {
            case -1: ROW(0, wB); break;
            case 0:  ROW(0, wA); ROW(1, wB); break;
            case 1:  ROW(1, wA); ROW(2, wB); break;
            case 2:  ROW(2, wA); ROW(3, wB); break;
            default: ROW(3, wA); break;    // j0 == 3
        }

        // fused norm (lane as pixel)
        const float axn = fmaxf(1.0f - fabsf(r0.x - Xp), 0.0f);
        const float ayn = fmaxf(1.0f - fabsf(r0.y - Yp), 0.0f);
        nrm = fmaf(r0.z, axn * ayn, nrm);

        r0 = r1; r1 = r2; r2 = r3; v0 = v1; v1 = v2;
    }

    // ---- epilogue: per-row LDS transpose (single wave, no barriers) ----
    const float inv = (nrm == 0.0f) ? 1.0f : (1.0f / nrm);
    s_inv[lane] = inv;

    float* ob = out + (size_t)b * C * HW;
    const int cq = lane >> 4;              // channel quarter 0..3
    for (int k = 0; k < 4; ++k) {          // bin row
#pragma unroll
        for (int px = 0; px < 16; ++px)
            st[px][lane] = acc[k * 16 + px];          // lane = channel
        const float iv = s_inv[k * 16 + pxx];
        const int ooff = (qy0 + k) * W + qx0 + pxx;
#pragma unroll
        for (int rr = 0; rr < 16; ++rr) {
            const int c = (rr << 2) | cq;
            ob[(size_t)c * HW + ooff] = st[pxx][c] * iv; // lanes 0-15: contiguous px
        }
    }
}

// ===================== MID TIER (R1 fast path) ==============================
__global__ __launch_bounds__(256) void splat_nhwc(
    const float* __restrict__ input,
    const float* __restrict__ flow,
    const float* __restrict__ metric,
    float* __restrict__ scr,
    float* __restrict__ norm)
{
    __shared__ float s_val[128][65];
    __shared__ float s_fx[128], s_fy[128], s_m[128];

    const int tid = threadIdx.x;
    const int nwg = gridDim.x;
    const int bid = blockIdx.x;
    const int swz = (bid & 7) * (nwg >> 3) + (bid >> 3);

    const int blockPix = swz * 128;
    const int b = blockPix / HW;
    const int pb = blockPix - b * HW;

    if (tid < 128) {
        const int p = pb + tid;
        const int y = p / W;
        const int x = p - y * W;
        s_fx[tid] = (float)x + flow[(b * 2 + 0) * HW + p];
        s_fy[tid] = (float)y + flow[(b * 2 + 1) * HW + p];
        s_m[tid]  = __expf(metric[b * HW + p]);
    }
    {
        const int sp = tid & 127;
        const int sc = tid >> 7;
        const float* ib = input + (size_t)b * C * HW + pb + sp;
#pragma unroll
        for (int c = 0; c < 32; ++c) {
            const int ch = 2 * c + sc;
            s_val[sp][ch] = ib[(size_t)ch * HW];
        }
    }
    __syncthreads();

    const int wave = tid >> 6;
    const int lane = tid & 63;
    float* __restrict__ sb = scr + (size_t)b * HW * 64;
    float* __restrict__ nb = norm + b * HW;

    for (int k = 0; k < 32; ++k) {
        const int j = (wave << 5) | k;
        const float fx = s_fx[j], fy = s_fy[j], m = s_m[j];
        const float v = s_val[j][lane] * m;

        const float x0f = floorf(fx), y0f = floorf(fy);
        const int x0 = (int)x0f, y0 = (int)y0f;
        const int x1 = x0 + 1,   y1 = y0 + 1;
        const float wx1 = fx - x0f, wx0 = 1.0f - wx1;
        const float wy1 = fy - y0f, wy0 = 1.0f - wy1;

        const bool vx0 = (x0 >= 0) & (x0 < W);
        const bool vx1 = (x1 >= 0) & (x1 < W);
        const bool vy0 = (y0 >= 0) & (y0 < H);
        const bool vy1 = (y1 >= 0) & (y1 < H);

        if (vx0 & vy0) {
            const float w = wx0 * wy0; const int t = y0 * W + x0;
            atomicAdd(sb + (size_t)t * 64 + lane, v * w);
            if (lane == 0) atomicAdd(nb + t, m * w);
        }
        if (vx1 & vy0) {
            const float w = wx1 * wy0; const int t = y0 * W + x1;
            atomicAdd(sb + (size_t)t * 64 + lane, v * w);
            if (lane == 0) atomicAdd(nb + t, m * w);
        }
        if (vx0 & vy1) {
            const float w = wx0 * wy1; const int t = y1 * W + x0;
            atomicAdd(sb + (size_t)t * 64 + lane, v * w);
            if (lane == 0) atomicAdd(nb + t, m * w);
        }
        if (vx1 & vy1) {
            const float w = wx1 * wy1; const int t = y1 * W + x1;
            atomicAdd(sb + (size_t)t * 64 + lane, v * w);
            if (lane == 0) atomicAdd(nb + t, m * w);
        }
    }
}

__global__ __launch_bounds__(256) void untranspose_norm(
    const float* __restrict__ scr,
    const float* __restrict__ norm,
    float* __restrict__ out)
{
    __shared__ float s_t[64][65];
    __shared__ float s_inv[64];

    const int tid = threadIdx.x;
    const int strips = HW / 64;
    const int b = blockIdx.x / strips;
    const int pblk = (blockIdx.x - b * strips) * 64;

    if (tid < 64) {
        float n = norm[b * HW + pblk + tid];
        s_inv[tid] = (n == 0.0f) ? 1.0f : (1.0f / n);
    }
    const float* sb = scr + ((size_t)b * HW + pblk) * 64;
#pragma unroll
    for (int r = 0; r < 16; ++r) {
        const int pr = r * 4 + (tid >> 6);
        const int c  = tid & 63;
        s_t[pr][c] = sb[(size_t)pr * 64 + c];
    }
    __syncthreads();

    float* ob = out + (size_t)b * C * HW + pblk;
#pragma unroll
    for (int r = 0; r < 16; ++r) {
        const int c   = r * 4 + (tid >> 6);
        const int pix = tid & 63;
        ob[(size_t)c * HW + pix] = s_t[pix][c] * s_inv[pix];
    }
}

// ===================== FALLBACK (naive) =====================================
__global__ void splat_kernel(const float* __restrict__ input,
                             const float* __restrict__ flow,
                             const float* __restrict__ metric,
                             float* __restrict__ out,
                             float* __restrict__ norm)
{
    int idx = blockIdx.x * blockDim.x + threadIdx.x;
    if (idx >= N * HW) return;
    int b = idx / HW;
    int p = idx - b * HW;
    int y = p / W;
    int x = p - y * W;

    float fx = (float)x + flow[(b * 2 + 0) * HW + p];
    float fy = (float)y + flow[(b * 2 + 1) * HW + p];
    float m  = __expf(metric[b * HW + p]);

    float x0f = floorf(fx), y0f = floorf(fy);
    int x0 = (int)x0f, y0 = (int)y0f;
    int x1 = x0 + 1,   y1 = y0 + 1;
    float wx1 = fx - x0f, wx0 = 1.0f - wx1;
    float wy1 = fy - y0f, wy0 = 1.0f - wy1;

    bool vx0 = (x0 >= 0) & (x0 < W);
    bool vx1 = (x1 >= 0) & (x1 < W);
    bool vy0 = (y0 >= 0) & (y0 < H);
    bool vy1 = (y1 >= 0) & (y1 < H);

    bool vNW = vx0 & vy0, vNE = vx1 & vy0, vSW = vx0 & vy1, vSE = vx1 & vy1;
    float wNW = wx0 * wy0, wNE = wx1 * wy0, wSW = wx0 * wy1, wSE = wx1 * wy1;
    int iNW = y0 * W + x0, iNE = y0 * W + x1, iSW = y1 * W + x0, iSE = y1 * W + x1;

    {
        float* nb = norm + b * HW;
        if (vNW) atomicAdd(nb + iNW, m * wNW);
        if (vNE) atomicAdd(nb + iNE, m * wNE);
        if (vSW) atomicAdd(nb + iSW, m * wSW);
        if (vSE) atomicAdd(nb + iSE, m * wSE);
    }

    const float* ib = input + (size_t)b * C * HW + p;
    float* ob = out + (size_t)b * C * HW;
#pragma unroll 4
    for (int c = 0; c < C; ++c) {
        float v = ib[(size_t)c * HW] * m;
        float* oc = ob + (size_t)c * HW;
        if (vNW) atomicAdd(oc + iNW, v * wNW);
        if (vNE) atomicAdd(oc + iNE, v * wNE);
        if (vSW) atomicAdd(oc + iSW, v * wSW);
        if (vSE) atomicAdd(oc + iSE, v * wSE);
    }
}

__global__ void norm_kernel(float* __restrict__ out,
                            const float* __restrict__ norm)
{
    int idx = blockIdx.x * blockDim.x + threadIdx.x;
    int total = N * C * HW / 4;
    if (idx >= total) return;

    int pixq = idx % (HW / 4);
    int bc   = idx / (HW / 4);
    int b    = bc / C;

    const float4* np4 = (const float4*)(norm + (size_t)b * HW);
    float4 n = np4[pixq];
    n.x = (n.x == 0.0f) ? 1.0f : n.x;
    n.y = (n.y == 0.0f) ? 1.0f : n.y;
    n.z = (n.z == 0.0f) ? 1.0f : n.z;
    n.w = (n.w == 0.0f) ? 1.0f : n.w;

    float4* o4 = (float4*)out;
    float4 v = o4[idx];
    v.x /= n.x; v.y /= n.y; v.z /= n.z; v.w /= n.w;
    o4[idx] = v;
}

// ============================================================================
extern "C" void kernel_launch(void* const* d_in, const int* in_sizes, int n_in,
                              void* d_out, int out_size, void* d_ws, size_t ws_size,
                              hipStream_t stream)
{
    const float* input  = (const float*)d_in[0];   // (4,64,256,448)
    const float* flow   = (const float*)d_in[1];   // (4,2,256,448)
    const float* metric = (const float*)d_in[2];   // (4,1,256,448)
    float* out = (float*)d_out;

    const size_t augBytes  = (size_t)N * HW * 64 * sizeof(float);   // 117.44 MB
    const size_t metaBytes = ((size_t)BINS * 2 + BINS + 1) * sizeof(unsigned);

    // Record-capacity tiers (16 B records). Expected usage ~1.33 * N*HW.
    const size_t capFull = (size_t)4 * N * HW;
    const size_t cap2x   = (size_t)2 * N * HW;
    const size_t cap15x  = (size_t)3 * N * HW / 2;

    auto need = [&](size_t capE) {
        return augBytes + capE * sizeof(float4) + metaBytes;
    };
    const size_t need_mid = augBytes + (size_t)N * HW * sizeof(float);

    size_t capE = 0;
    if      (ws_size >= need(capFull)) capE = capFull;
    else if (ws_size >= need(cap2x))   capE = cap2x;
    else if (ws_size >= need(cap15x))  capE = cap15x;

    if (capE) {
        float*    aug      = (float*)d_ws;
        float4*   recs     = (float4*)((char*)d_ws + augBytes);
        unsigned* counts   = (unsigned*)(recs + capE);
        unsigned* cursor   = counts + BINS;
        unsigned* segstart = cursor + BINS;

        hipMemsetAsync(counts, 0, 2 * BINS * sizeof(unsigned), stream);
        count_kernel<<<N * HW / 1024, 1024, 0, stream>>>(flow, counts);
        scan_kernel<<<1, 1024, 0, stream>>>(counts, segstart, (unsigned)capE);
        fill2_kernel<<<N * HW / 1024, 1024, 0, stream>>>(flow, metric, segstart,
                                                         cursor, recs, (unsigned)capE);
        augT_kernel<<<N * HW / 128, 256, 0, stream>>>(input, metric, aug);
        gather5<<<BINS, 64, 0, stream>>>(recs, aug, segstart, out);
    } else if (ws_size >= need_mid) {
        float* scr  = (float*)d_ws;
        float* norm = scr + (size_t)N * HW * 64;
        hipMemsetAsync(scr, 0, need_mid, stream);

        splat_nhwc<<<N * HW / 128, 256, 0, stream>>>(input, flow, metric, scr, norm);
        untranspose_norm<<<N * (HW / 64), 256, 0, stream>>>(scr, norm, out);
    } else {
        float* norm = (float*)d_ws;
        hipMemsetAsync(out,  0, (size_t)N * C * HW * sizeof(float), stream);
        hipMemsetAsync(norm, 0, (size_t)N * HW * sizeof(float), stream);

        splat_kernel<<<(N * HW + 255) / 256, 256, 0, stream>>>(input, flow, metric, out, norm);
        int total = N * C * HW / 4;
        norm_kernel<<<(total + 255) / 256, 256, 0, stream>>>(out, norm);
    }
}

// Round 9
// 492.732 us; speedup vs baseline: 3.5167x; 3.5167x over previous
//
#include <hip/hip_runtime.h>

constexpr int N = 4;
constexpr int C = 64;
constexpr int H = 256;
constexpr int W = 448;
constexpr int HW = H * W;

// 16x4 bins (one wave owns one bin; 64 px)
constexpr int BSX = 16;
constexpr int BSY = 4;
constexpr int BW_ = W / BSX;           // 28
constexpr int BH_ = H / BSY;           // 64
constexpr int BINS_PB = BW_ * BH_;     // 1792 per batch
constexpr int BINS = N * BINS_PB;      // 7168

// ===================== GATHER PATH (R9) =====================================
// R8 post-mortem: __launch_bounds__(64,4) capped VGPR at 128; allocator
// couldn't fit acc[64]+pipeline (~115-130 demand), SPILLED acc to scratch:
// VGPR_Count=64, WRITE_SIZE=4.1GB (vs 120MB real output), 1553us. The R8
// structural ideas were never tested. R9 = identical kernel with
// __launch_bounds__(64,2) (cap 256): zero spill, HW still gives 4 waves/SIMD
// at VGPR<=128 (16 independent 1-wave blocks/CU).
// R8 ideas under test: 1-wave blocks; records 3-ahead / rows 2-ahead;
// wave-uniform floor(fyl) switch -> only live rows (32 fmacs); fused norm.

__device__ __forceinline__ int binsOf(int x0, int y0, int bins[4]) {
    const int x1 = x0 + 1, y1 = y0 + 1;
    int n = 0;
    int bxA = -2, bxB = -2, byA = -2, byB = -2;
    if ((unsigned)x0 < (unsigned)W) bxA = x0 >> 4;
    if ((unsigned)x1 < (unsigned)W) { const int t = x1 >> 4; if (t != bxA) bxB = t; }
    if ((unsigned)y0 < (unsigned)H) byA = y0 >> 2;
    if ((unsigned)y1 < (unsigned)H) { const int t = y1 >> 2; if (t != byA) byB = t; }
    if (byA >= 0) {
        if (bxA >= 0) bins[n++] = byA * BW_ + bxA;
        if (bxB >= 0) bins[n++] = byA * BW_ + bxB;
    }
    if (byB >= 0) {
        if (bxA >= 0) bins[n++] = byB * BW_ + bxA;
        if (bxB >= 0) bins[n++] = byB * BW_ + bxB;
    }
    return n;
}

// count: flow-only pass, LDS-aggregated per-batch bin counts.
__global__ __launch_bounds__(1024) void count_kernel(
    const float* __restrict__ flow,
    unsigned* __restrict__ counts)    // [BINS]
{
    __shared__ unsigned lcnt[BINS_PB];
    const int tid = threadIdx.x;
    const int idx = blockIdx.x * 1024 + tid;     // HW % 1024 == 0
    const int b = idx / HW;
    const int p = idx - b * HW;
    const int y = p / W;
    const int x = p - y * W;

    for (int i = tid; i < BINS_PB; i += 1024) lcnt[i] = 0;
    __syncthreads();

    const float fx = (float)x + flow[(b * 2 + 0) * HW + p];
    const float fy = (float)y + flow[(b * 2 + 1) * HW + p];
    const int x0 = (int)floorf(fx), y0 = (int)floorf(fy);

    int bn[4];
    const int nb = binsOf(x0, y0, bn);
    for (int i = 0; i < nb; ++i) atomicAdd(&lcnt[bn[i]], 1u);
    __syncthreads();

    for (int i = tid; i < BINS_PB; i += 1024)
        if (lcnt[i]) atomicAdd(&counts[b * BINS_PB + i], lcnt[i]);
}

// scan: exclusive prefix sum of 7168 counts (= 1024*7), clamped at capE.
__global__ __launch_bounds__(1024) void scan_kernel(
    const unsigned* __restrict__ counts,
    unsigned* __restrict__ segstart,  // [BINS+1]
    unsigned capE)
{
    __shared__ unsigned lsum[1024];
    const int tid = threadIdx.x;
    unsigned v[7];
    unsigned s = 0;
#pragma unroll
    for (int i = 0; i < 7; ++i) { v[i] = counts[tid * 7 + i]; s += v[i]; }
    lsum[tid] = s;
    __syncthreads();
    for (int off = 1; off < 1024; off <<= 1) {
        const unsigned t = (tid >= off) ? lsum[tid - off] : 0u;
        __syncthreads();
        lsum[tid] += t;
        __syncthreads();
    }
    unsigned run = lsum[tid] - s;
#pragma unroll
    for (int i = 0; i < 7; ++i) {
        segstart[tid * 7 + i] = run < capE ? run : capE;
        run += v[i];
    }
    if (tid == 1023) segstart[BINS] = run < capE ? run : capE;
}

// fill2: all 1024 threads active; one source each; write 16-B records
// {fx,fy,m,bitcast(p)} via direct per-bin cursor atomics.
__global__ __launch_bounds__(1024) void fill2_kernel(
    const float* __restrict__ flow,
    const float* __restrict__ metric,
    const unsigned* __restrict__ segstart,
    unsigned* __restrict__ cursor,    // [BINS], pre-zeroed
    float4* __restrict__ recs,        // [capE]
    unsigned capE)
{
    const int tid = threadIdx.x;
    const int idx = blockIdx.x * 1024 + tid;     // HW % 1024 == 0
    const int b = idx / HW;
    const int p = idx - b * HW;
    const int y = p / W;
    const int x = p - y * W;

    const float fx = (float)x + flow[(b * 2 + 0) * HW + p];
    const float fy = (float)y + flow[(b * 2 + 1) * HW + p];
    const float m  = __expf(metric[b * HW + p]);
    const int x0 = (int)floorf(fx), y0 = (int)floorf(fy);

    int bn[4];
    const int nb = binsOf(x0, y0, bn);
    const float4 rec = make_float4(fx, fy, m, __int_as_float(p));
    const int tb = b * BINS_PB;
    for (int i = 0; i < nb; ++i) {
        const unsigned off = atomicAdd(&cursor[tb + bn[i]], 1u);
        const unsigned slot = segstart[tb + bn[i]] + off;
        if (slot < capE) recs[slot] = rec;
    }
}

// augT: pure streaming NCHW -> NHWC transpose, premultiplied by m.
__global__ __launch_bounds__(256) void augT_kernel(
    const float* __restrict__ input,
    const float* __restrict__ metric,
    float* __restrict__ aug)          // [N*HW][64]
{
    __shared__ float s_val[128][65];
    __shared__ float s_m[128];

    const int tid = threadIdx.x;
    const int blockPix = blockIdx.x * 128;       // HW % 128 == 0
    const int b = blockPix / HW;
    const int pb = blockPix - b * HW;

    if (tid < 128)
        s_m[tid] = __expf(metric[b * HW + pb + tid]);

    {
        const int sp = tid & 127;
        const int sc = tid >> 7;
        const float* ib = input + (size_t)b * C * HW + pb + sp;
#pragma unroll
        for (int c = 0; c < 32; ++c) {
            const int ch = 2 * c + sc;
            s_val[sp][ch] = ib[(size_t)ch * HW];
        }
    }
    __syncthreads();

    const int wv = tid >> 6, ln = tid & 63;
    float* abase = aug + ((size_t)b * HW + pb) * 64;
#pragma unroll
    for (int it = 0; it < 32; ++it) {
        const int j = (wv << 5) + it;
        abase[(size_t)j * 64 + ln] = s_val[j][ln] * s_m[j];
    }
}

// Static-index row accumulate (J must be a literal at each call site).
#define ROW(J, WGT) do { const float tv_ = v0 * (WGT);                    \
    _Pragma("unroll")                                                     \
    for (int i_ = 0; i_ < 16; ++i_)                                       \
        acc[(J) * 16 + i_] = fmaf(tv_, axx[i_], acc[(J) * 16 + i_]);      \
} while (0)

// gather5: grid = BINS blocks x 64 threads (1 wave = 1 bin).
// lane = CHANNEL; acc[64] = pixels (static index). Records 3-ahead, rows
// 2-ahead. Wave-uniform switch on floor(fyl) -> only live rows. Norm fused.
// launch_bounds(64,2): VGPR cap 256 -> no spill; HW gives 4 waves/SIMD at
// VGPR<=128 regardless of the bound.
__global__ __launch_bounds__(64, 2) void gather5(
    const float4* __restrict__ recs,
    const float* __restrict__ aug,
    const unsigned* __restrict__ segstart,
    float* __restrict__ out)
{
    __shared__ float st[16][65];      // 4.2 KB
    __shared__ float s_inv[64];

    const int lane = threadIdx.x;

    // XCD-contiguous swizzle (grid 7168 % 8 == 0)
    const int nwg = gridDim.x;
    const int bid = blockIdx.x;
    const int g   = (bid & 7) * (nwg >> 3) + (bid >> 3);

    const int b   = g / BINS_PB;
    const int bin = g - b * BINS_PB;
    const int by  = bin / BW_;
    const int bx  = bin - by * BW_;
    const int qx0 = bx * BSX;
    const int qy0 = by * BSY;

    // norm identity for this lane (lane as pixel)
    const int pxx = lane & 15, pyy = lane >> 4;
    const float Xp = (float)(qx0 + pxx);
    const float Yp = (float)(qy0 + pyy);

    float acc[64];
#pragma unroll
    for (int i = 0; i < 64; ++i) acc[i] = 0.0f;
    float nrm = 0.0f;

    const int start = (int)segstart[g];
    const int end   = (int)segstart[g + 1];
    const float* ab = aug + (size_t)b * HW * 64;

    const float4 Z = make_float4(0.0f, 0.0f, 0.0f, __int_as_float(0));
    float4 r0 = Z, r1 = Z, r2 = Z;
    float v0 = 0.0f, v1 = 0.0f;
    if (start + 0 < end) r0 = recs[start + 0];
    if (start + 1 < end) r1 = recs[start + 1];
    if (start + 2 < end) r2 = recs[start + 2];
    if (start + 0 < end) {
        const int p0 = __builtin_amdgcn_readfirstlane(__float_as_int(r0.w));
        v0 = ab[(size_t)p0 * 64 + lane];
    }
    if (start + 1 < end) {
        const int p1 = __builtin_amdgcn_readfirstlane(__float_as_int(r1.w));
        v1 = ab[(size_t)p1 * 64 + lane];
    }

    for (int e = start; e < end; ++e) {
        // keep records 3 ahead, rows 2 ahead
        float4 r3 = Z;
        if (e + 3 < end) r3 = recs[e + 3];
        float v2 = 0.0f;
        if (e + 2 < end) {
            const int p2 = __builtin_amdgcn_readfirstlane(__float_as_int(r2.w));
            v2 = ab[(size_t)p2 * 64 + lane];
        }

        // ---- compute with r0, v0 ----
        const float fxl = r0.x - (float)qx0;
        const float fyl = r0.y - (float)qy0;
        float axx[16];
#pragma unroll
        for (int i = 0; i < 16; ++i)
            axx[i] = fmaxf(1.0f - fabsf(fxl - (float)i), 0.0f);

        const float fyf = floorf(fyl);
        const int   j0  = (int)fyf;        // wave-uniform, in [-1, 3]
        const float fr  = fyl - fyf;
        const float wA  = 1.0f - fr, wB = fr;
        switch (j0) {
            case -1: ROW(0, wB); break;
            case 0:  ROW(0, wA); ROW(1, wB); break;
            case 1:  ROW(1, wA); ROW(2, wB); break;
            case 2:  ROW(2, wA); ROW(3, wB); break;
            default: ROW(3, wA); break;    // j0 == 3
        }

        // fused norm (lane as pixel)
        const float axn = fmaxf(1.0f - fabsf(r0.x - Xp), 0.0f);
        const float ayn = fmaxf(1.0f - fabsf(r0.y - Yp), 0.0f);
        nrm = fmaf(r0.z, axn * ayn, nrm);

        r0 = r1; r1 = r2; r2 = r3; v0 = v1; v1 = v2;
    }

    // ---- epilogue: per-row LDS transpose (single wave, no barriers) ----
    const float inv = (nrm == 0.0f) ? 1.0f : (1.0f / nrm);
    s_inv[lane] = inv;

    float* ob = out + (size_t)b * C * HW;
    const int cq = lane >> 4;              // channel quarter 0..3
    for (int k = 0; k < 4; ++k) {          // bin row
#pragma unroll
        for (int px = 0; px < 16; ++px)
            st[px][lane] = acc[k * 16 + px];          // lane = channel
        const float iv = s_inv[k * 16 + pxx];
        const int ooff = (qy0 + k) * W + qx0 + pxx;
#pragma unroll
        for (int rr = 0; rr < 16; ++rr) {
            const int c = (rr << 2) | cq;
            ob[(size_t)c * HW + ooff] = st[pxx][c] * iv; // lanes 0-15: contiguous px
        }
    }
}

// ===================== MID TIER (R1 fast path) ==============================
__global__ __launch_bounds__(256) void splat_nhwc(
    const float* __restrict__ input,
    const float* __restrict__ flow,
    const float* __restrict__ metric,
    float* __restrict__ scr,
    float* __restrict__ norm)
{
    __shared__ float s_val[128][65];
    __shared__ float s_fx[128], s_fy[128], s_m[128];

    const int tid = threadIdx.x;
    const int nwg = gridDim.x;
    const int bid = blockIdx.x;
    const int swz = (bid & 7) * (nwg >> 3) + (bid >> 3);

    const int blockPix = swz * 128;
    const int b = blockPix / HW;
    const int pb = blockPix - b * HW;

    if (tid < 128) {
        const int p = pb + tid;
        const int y = p / W;
        const int x = p - y * W;
        s_fx[tid] = (float)x + flow[(b * 2 + 0) * HW + p];
        s_fy[tid] = (float)y + flow[(b * 2 + 1) * HW + p];
        s_m[tid]  = __expf(metric[b * HW + p]);
    }
    {
        const int sp = tid & 127;
        const int sc = tid >> 7;
        const float* ib = input + (size_t)b * C * HW + pb + sp;
#pragma unroll
        for (int c = 0; c < 32; ++c) {
            const int ch = 2 * c + sc;
            s_val[sp][ch] = ib[(size_t)ch * HW];
        }
    }
    __syncthreads();

    const int wave = tid >> 6;
    const int lane = tid & 63;
    float* __restrict__ sb = scr + (size_t)b * HW * 64;
    float* __restrict__ nb = norm + b * HW;

    for (int k = 0; k < 32; ++k) {
        const int j = (wave << 5) | k;
        const float fx = s_fx[j], fy = s_fy[j], m = s_m[j];
        const float v = s_val[j][lane] * m;

        const float x0f = floorf(fx), y0f = floorf(fy);
        const int x0 = (int)x0f, y0 = (int)y0f;
        const int x1 = x0 + 1,   y1 = y0 + 1;
        const float wx1 = fx - x0f, wx0 = 1.0f - wx1;
        const float wy1 = fy - y0f, wy0 = 1.0f - wy1;

        const bool vx0 = (x0 >= 0) & (x0 < W);
        const bool vx1 = (x1 >= 0) & (x1 < W);
        const bool vy0 = (y0 >= 0) & (y0 < H);
        const bool vy1 = (y1 >= 0) & (y1 < H);

        if (vx0 & vy0) {
            const float w = wx0 * wy0; const int t = y0 * W + x0;
            atomicAdd(sb + (size_t)t * 64 + lane, v * w);
            if (lane == 0) atomicAdd(nb + t, m * w);
        }
        if (vx1 & vy0) {
            const float w = wx1 * wy0; const int t = y0 * W + x1;
            atomicAdd(sb + (size_t)t * 64 + lane, v * w);
            if (lane == 0) atomicAdd(nb + t, m * w);
        }
        if (vx0 & vy1) {
            const float w = wx0 * wy1; const int t = y1 * W + x0;
            atomicAdd(sb + (size_t)t * 64 + lane, v * w);
            if (lane == 0) atomicAdd(nb + t, m * w);
        }
        if (vx1 & vy1) {
            const float w = wx1 * wy1; const int t = y1 * W + x1;
            atomicAdd(sb + (size_t)t * 64 + lane, v * w);
            if (lane == 0) atomicAdd(nb + t, m * w);
        }
    }
}

__global__ __launch_bounds__(256) void untranspose_norm(
    const float* __restrict__ scr,
    const float* __restrict__ norm,
    float* __restrict__ out)
{
    __shared__ float s_t[64][65];
    __shared__ float s_inv[64];

    const int tid = threadIdx.x;
    const int strips = HW / 64;
    const int b = blockIdx.x / strips;
    const int pblk = (blockIdx.x - b * strips) * 64;

    if (tid < 64) {
        float n = norm[b * HW + pblk + tid];
        s_inv[tid] = (n == 0.0f) ? 1.0f : (1.0f / n);
    }
    const float* sb = scr + ((size_t)b * HW + pblk) * 64;
#pragma unroll
    for (int r = 0; r < 16; ++r) {
        const int pr = r * 4 + (tid >> 6);
        const int c  = tid & 63;
        s_t[pr][c] = sb[(size_t)pr * 64 + c];
    }
    __syncthreads();

    float* ob = out + (size_t)b * C * HW + pblk;
#pragma unroll
    for (int r = 0; r < 16; ++r) {
        const int c   = r * 4 + (tid >> 6);
        const int pix = tid & 63;
        ob[(size_t)c * HW + pix] = s_t[pix][c] * s_inv[pix];
    }
}

// ===================== FALLBACK (naive) =====================================
__global__ void splat_kernel(const float* __restrict__ input,
                             const float* __restrict__ flow,
                             const float* __restrict__ metric,
                             float* __restrict__ out,
                             float* __restrict__ norm)
{
    int idx = blockIdx.x * blockDim.x + threadIdx.x;
    if (idx >= N * HW) return;
    int b = idx / HW;
    int p = idx - b * HW;
    int y = p / W;
    int x = p - y * W;

    float fx = (float)x + flow[(b * 2 + 0) * HW + p];
    float fy = (float)y + flow[(b * 2 + 1) * HW + p];
    float m  = __expf(metric[b * HW + p]);

    float x0f = floorf(fx), y0f = floorf(fy);
    int x0 = (int)x0f, y0 = (int)y0f;
    int x1 = x0 + 1,   y1 = y0 + 1;
    float wx1 = fx - x0f, wx0 = 1.0f - wx1;
    float wy1 = fy - y0f, wy0 = 1.0f - wy1;

    bool vx0 = (x0 >= 0) & (x0 < W);
    bool vx1 = (x1 >= 0) & (x1 < W);
    bool vy0 = (y0 >= 0) & (y0 < H);
    bool vy1 = (y1 >= 0) & (y1 < H);

    bool vNW = vx0 & vy0, vNE = vx1 & vy0, vSW = vx0 & vy1, vSE = vx1 & vy1;
    float wNW = wx0 * wy0, wNE = wx1 * wy0, wSW = wx0 * wy1, wSE = wx1 * wy1;
    int iNW = y0 * W + x0, iNE = y0 * W + x1, iSW = y1 * W + x0, iSE = y1 * W + x1;

    {
        float* nb = norm + b * HW;
        if (vNW) atomicAdd(nb + iNW, m * wNW);
        if (vNE) atomicAdd(nb + iNE, m * wNE);
        if (vSW) atomicAdd(nb + iSW, m * wSW);
        if (vSE) atomicAdd(nb + iSE, m * wSE);
    }

    const float* ib = input + (size_t)b * C * HW + p;
    float* ob = out + (size_t)b * C * HW;
#pragma unroll 4
    for (int c = 0; c < C; ++c) {
        float v = ib[(size_t)c * HW] * m;
        float* oc = ob + (size_t)c * HW;
        if (vNW) atomicAdd(oc + iNW, v * wNW);
        if (vNE) atomicAdd(oc + iNE, v * wNE);
        if (vSW) atomicAdd(oc + iSW, v * wSW);
        if (vSE) atomicAdd(oc + iSE, v * wSE);
    }
}

__global__ void norm_kernel(float* __restrict__ out,
                            const float* __restrict__ norm)
{
    int idx = blockIdx.x * blockDim.x + threadIdx.x;
    int total = N * C * HW / 4;
    if (idx >= total) return;

    int pixq = idx % (HW / 4);
    int bc   = idx / (HW / 4);
    int b    = bc / C;

    const float4* np4 = (const float4*)(norm + (size_t)b * HW);
    float4 n = np4[pixq];
    n.x = (n.x == 0.0f) ? 1.0f : n.x;
    n.y = (n.y == 0.0f) ? 1.0f : n.y;
    n.z = (n.z == 0.0f) ? 1.0f : n.z;
    n.w = (n.w == 0.0f) ? 1.0f : n.w;

    float4* o4 = (float4*)out;
    float4 v = o4[idx];
    v.x /= n.x; v.y /= n.y; v.z /= n.z; v.w /= n.w;
    o4[idx] = v;
}

// ============================================================================
extern "C" void kernel_launch(void* const* d_in, const int* in_sizes, int n_in,
                              void* d_out, int out_size, void* d_ws, size_t ws_size,
                              hipStream_t stream)
{
    const float* input  = (const float*)d_in[0];   // (4,64,256,448)
    const float* flow   = (const float*)d_in[1];   // (4,2,256,448)
    const float* metric = (const float*)d_in[2];   // (4,1,256,448)
    float* out = (float*)d_out;

    const size_t augBytes  = (size_t)N * HW * 64 * sizeof(float);   // 117.44 MB
    const size_t metaBytes = ((size_t)BINS * 2 + BINS + 1) * sizeof(unsigned);

    // Record-capacity tiers (16 B records). Expected usage ~1.33 * N*HW.
    const size_t capFull = (size_t)4 * N * HW;
    const size_t cap2x   = (size_t)2 * N * HW;
    const size_t cap15x  = (size_t)3 * N * HW / 2;

    auto need = [&](size_t capE) {
        return augBytes + capE * sizeof(float4) + metaBytes;
    };
    const size_t need_mid = augBytes + (size_t)N * HW * sizeof(float);

    size_t capE = 0;
    if      (ws_size >= need(capFull)) capE = capFull;
    else if (ws_size >= need(cap2x))   capE = cap2x;
    else if (ws_size >= need(cap15x))  capE = cap15x;

    if (capE) {
        float*    aug      = (float*)d_ws;
        float4*   recs     = (float4*)((char*)d_ws + augBytes);
        unsigned* counts   = (unsigned*)(recs + capE);
        unsigned* cursor   = counts + BINS;
        unsigned* segstart = cursor + BINS;

        hipMemsetAsync(counts, 0, 2 * BINS * sizeof(unsigned), stream);
        count_kernel<<<N * HW / 1024, 1024, 0, stream>>>(flow, counts);
        scan_kernel<<<1, 1024, 0, stream>>>(counts, segstart, (unsigned)capE);
        fill2_kernel<<<N * HW / 1024, 1024, 0, stream>>>(flow, metric, segstart,
                                                         cursor, recs, (unsigned)capE);
        augT_kernel<<<N * HW / 128, 256, 0, stream>>>(input, metric, aug);
        gather5<<<BINS, 64, 0, stream>>>(recs, aug, segstart, out);
    } else if (ws_size >= need_mid) {
        float* scr  = (float*)d_ws;
        float* norm = scr + (size_t)N * HW * 64;
        hipMemsetAsync(scr, 0, need_mid, stream);

        splat_nhwc<<<N * HW / 128, 256, 0, stream>>>(input, flow, metric, scr, norm);
        untranspose_norm<<<N * (HW / 64), 256, 0, stream>>>(scr, norm, out);
    } else {
        float* norm = (float*)d_ws;
        hipMemsetAsync(out,  0, (size_t)N * C * HW * sizeof(float), stream);
        hipMemsetAsync(norm, 0, (size_t)N * HW * sizeof(float), stream);

        splat_kernel<<<(N * HW + 255) / 256, 256, 0, stream>>>(input, flow, metric, out, norm);
        int total = N * C * HW / 4;
        norm_kernel<<<(total + 255) / 256, 256, 0, stream>>>(out, norm);
    }
}

// Round 10
// 387.969 us; speedup vs baseline: 4.4663x; 1.2700x over previous
//
#include <hip/hip_runtime.h>

constexpr int N = 4;
constexpr int C = 64;
constexpr int H = 256;
constexpr int W = 448;
constexpr int HW = H * W;

// 4x4 bins (one wave owns one bin; 16 px)
constexpr int BSX = 4;
constexpr int BSY = 4;
constexpr int BW_ = W / BSX;           // 112
constexpr int BH_ = H / BSY;           // 64
constexpr int BINS_PB = BW_ * BH_;     // 7168 per batch
constexpr int BINS = N * BINS_PB;      // 28672

// ===================== GATHER PATH (R10) ====================================
// R9 post-mortem: spill fixed, gather5 = 257us with VALUBusy 78% at occ 18%
// -> genuinely VALU-issue-bound. Per entry ~400 cyc issued but useful work is
// 4 px x 64 ch = 4 lane-fmacs; the 16-wide dense-x sweep (axx[16] + 32 fmacs)
// is an 8x x-axis waste forced by static acc indexing.
// R10: 4x4 bins. axx[4] + y-switch (2 live rows x 5 fmacs) -> ~50 VALU/entry.
// Records 610K -> 716K (+17%, E=1.56/source) -- a good trade when issue-bound.
// acc[16] -> VGPR ~65 -> more waves to cover VMEM. Norm LDS eliminated:
// lanes l, l+16, l+32, l+48 compute identical nrm (depends on lane&15 only),
// so each lane already holds the inv for its epilogue pixel.

__device__ __forceinline__ int binsOf(int x0, int y0, int bins[4]) {
    const int x1 = x0 + 1, y1 = y0 + 1;
    int n = 0;
    int bxA = -2, bxB = -2, byA = -2, byB = -2;
    if ((unsigned)x0 < (unsigned)W) bxA = x0 >> 2;
    if ((unsigned)x1 < (unsigned)W) { const int t = x1 >> 2; if (t != bxA) bxB = t; }
    if ((unsigned)y0 < (unsigned)H) byA = y0 >> 2;
    if ((unsigned)y1 < (unsigned)H) { const int t = y1 >> 2; if (t != byA) byB = t; }
    if (byA >= 0) {
        if (bxA >= 0) bins[n++] = byA * BW_ + bxA;
        if (bxB >= 0) bins[n++] = byA * BW_ + bxB;
    }
    if (byB >= 0) {
        if (bxA >= 0) bins[n++] = byB * BW_ + bxA;
        if (bxB >= 0) bins[n++] = byB * BW_ + bxB;
    }
    return n;
}

// count: flow-only pass, LDS-aggregated per-batch bin counts (28 KB LDS).
__global__ __launch_bounds__(1024) void count_kernel(
    const float* __restrict__ flow,
    unsigned* __restrict__ counts)    // [BINS]
{
    __shared__ unsigned lcnt[BINS_PB];
    const int tid = threadIdx.x;
    const int idx = blockIdx.x * 1024 + tid;     // HW % 1024 == 0
    const int b = idx / HW;
    const int p = idx - b * HW;
    const int y = p / W;
    const int x = p - y * W;

    for (int i = tid; i < BINS_PB; i += 1024) lcnt[i] = 0;
    __syncthreads();

    const float fx = (float)x + flow[(b * 2 + 0) * HW + p];
    const float fy = (float)y + flow[(b * 2 + 1) * HW + p];
    const int x0 = (int)floorf(fx), y0 = (int)floorf(fy);

    int bn[4];
    const int nb = binsOf(x0, y0, bn);
    for (int i = 0; i < nb; ++i) atomicAdd(&lcnt[bn[i]], 1u);
    __syncthreads();

    for (int i = tid; i < BINS_PB; i += 1024)
        if (lcnt[i]) atomicAdd(&counts[b * BINS_PB + i], lcnt[i]);
}

// scan: exclusive prefix sum of 28672 counts (= 1024*28), clamped at capE.
__global__ __launch_bounds__(1024) void scan_kernel(
    const unsigned* __restrict__ counts,
    unsigned* __restrict__ segstart,  // [BINS+1]
    unsigned capE)
{
    __shared__ unsigned lsum[1024];
    const int tid = threadIdx.x;
    constexpr int VPT = BINS / 1024;  // 28
    unsigned v[VPT];
    unsigned s = 0;
#pragma unroll
    for (int i = 0; i < VPT; ++i) { v[i] = counts[tid * VPT + i]; s += v[i]; }
    lsum[tid] = s;
    __syncthreads();
    for (int off = 1; off < 1024; off <<= 1) {
        const unsigned t = (tid >= off) ? lsum[tid - off] : 0u;
        __syncthreads();
        lsum[tid] += t;
        __syncthreads();
    }
    unsigned run = lsum[tid] - s;
#pragma unroll
    for (int i = 0; i < VPT; ++i) {
        segstart[tid * VPT + i] = run < capE ? run : capE;
        run += v[i];
    }
    if (tid == 1023) segstart[BINS] = run < capE ? run : capE;
}

// fill2: all 1024 threads active; one source each; write 16-B records
// {fx,fy,m,bitcast(p)} via direct per-bin cursor atomics (~25 RMW/addr).
__global__ __launch_bounds__(1024) void fill2_kernel(
    const float* __restrict__ flow,
    const float* __restrict__ metric,
    const unsigned* __restrict__ segstart,
    unsigned* __restrict__ cursor,    // [BINS], pre-zeroed
    float4* __restrict__ recs,        // [capE]
    unsigned capE)
{
    const int tid = threadIdx.x;
    const int idx = blockIdx.x * 1024 + tid;     // HW % 1024 == 0
    const int b = idx / HW;
    const int p = idx - b * HW;
    const int y = p / W;
    const int x = p - y * W;

    const float fx = (float)x + flow[(b * 2 + 0) * HW + p];
    const float fy = (float)y + flow[(b * 2 + 1) * HW + p];
    const float m  = __expf(metric[b * HW + p]);
    const int x0 = (int)floorf(fx), y0 = (int)floorf(fy);

    int bn[4];
    const int nb = binsOf(x0, y0, bn);
    const float4 rec = make_float4(fx, fy, m, __int_as_float(p));
    const int tb = b * BINS_PB;
    for (int i = 0; i < nb; ++i) {
        const unsigned off = atomicAdd(&cursor[tb + bn[i]], 1u);
        const unsigned slot = segstart[tb + bn[i]] + off;
        if (slot < capE) recs[slot] = rec;
    }
}

// augT: pure streaming NCHW -> NHWC transpose, premultiplied by m.
__global__ __launch_bounds__(256) void augT_kernel(
    const float* __restrict__ input,
    const float* __restrict__ metric,
    float* __restrict__ aug)          // [N*HW][64]
{
    __shared__ float s_val[128][65];
    __shared__ float s_m[128];

    const int tid = threadIdx.x;
    const int blockPix = blockIdx.x * 128;       // HW % 128 == 0
    const int b = blockPix / HW;
    const int pb = blockPix - b * HW;

    if (tid < 128)
        s_m[tid] = __expf(metric[b * HW + pb + tid]);

    {
        const int sp = tid & 127;
        const int sc = tid >> 7;
        const float* ib = input + (size_t)b * C * HW + pb + sp;
#pragma unroll
        for (int c = 0; c < 32; ++c) {
            const int ch = 2 * c + sc;
            s_val[sp][ch] = ib[(size_t)ch * HW];
        }
    }
    __syncthreads();

    const int wv = tid >> 6, ln = tid & 63;
    float* abase = aug + ((size_t)b * HW + pb) * 64;
#pragma unroll
    for (int it = 0; it < 32; ++it) {
        const int j = (wv << 5) + it;
        abase[(size_t)j * 64 + ln] = s_val[j][ln] * s_m[j];
    }
}

// Static-index row accumulate (J must be a literal at each call site).
#define ROW4(J, WGT) do { const float tv_ = v0 * (WGT);                   \
    _Pragma("unroll")                                                     \
    for (int i_ = 0; i_ < 4; ++i_)                                        \
        acc[(J) * 4 + i_] = fmaf(tv_, axx[i_], acc[(J) * 4 + i_]);        \
} while (0)

// gather6: grid = BINS blocks x 64 threads (1 wave = 1 bin of 4x4 px).
// lane = CHANNEL; acc[16] = pixels (static index). Records 3-ahead, rows
// 2-ahead. Wave-uniform switch on floor(fyl) -> only live rows (<=10 fmacs).
// Norm fused; each lane's nrm IS the inv for its epilogue pixel (lane&15).
__global__ __launch_bounds__(64, 2) void gather6(
    const float4* __restrict__ recs,
    const float* __restrict__ aug,
    const unsigned* __restrict__ segstart,
    float* __restrict__ out)
{
    __shared__ float st[16][65];      // 4.2 KB transpose buffer

    const int lane = threadIdx.x;

    // XCD-contiguous swizzle (grid 28672 % 8 == 0)
    const int nwg = gridDim.x;
    const int bid = blockIdx.x;
    const int g   = (bid & 7) * (nwg >> 3) + (bid >> 3);

    const int b   = g / BINS_PB;
    const int bin = g - b * BINS_PB;
    const int by  = bin / BW_;
    const int bx  = bin - by * BW_;
    const int qx0 = bx * BSX;
    const int qy0 = by * BSY;

    // norm identity: pixel (lane&15) -> (x = lane&3, y = (lane>>2)&3).
    // Lanes l, l+16, l+32, l+48 compute identical nrm.
    const float Xp = (float)(qx0 + (lane & 3));
    const float Yp = (float)(qy0 + ((lane >> 2) & 3));

    float acc[16];
#pragma unroll
    for (int i = 0; i < 16; ++i) acc[i] = 0.0f;
    float nrm = 0.0f;

    const int start = (int)segstart[g];
    const int end   = (int)segstart[g + 1];
    const float* ab = aug + (size_t)b * HW * 64;

    const float4 Z = make_float4(0.0f, 0.0f, 0.0f, __int_as_float(0));
    float4 r0 = Z, r1 = Z, r2 = Z;
    float v0 = 0.0f, v1 = 0.0f;
    if (start + 0 < end) r0 = recs[start + 0];
    if (start + 1 < end) r1 = recs[start + 1];
    if (start + 2 < end) r2 = recs[start + 2];
    if (start + 0 < end) {
        const int p0 = __builtin_amdgcn_readfirstlane(__float_as_int(r0.w));
        v0 = ab[(size_t)p0 * 64 + lane];
    }
    if (start + 1 < end) {
        const int p1 = __builtin_amdgcn_readfirstlane(__float_as_int(r1.w));
        v1 = ab[(size_t)p1 * 64 + lane];
    }

    for (int e = start; e < end; ++e) {
        // keep records 3 ahead, rows 2 ahead
        float4 r3 = Z;
        if (e + 3 < end) r3 = recs[e + 3];
        float v2 = 0.0f;
        if (e + 2 < end) {
            const int p2 = __builtin_amdgcn_readfirstlane(__float_as_int(r2.w));
            v2 = ab[(size_t)p2 * 64 + lane];
        }

        // ---- compute with r0, v0 ----
        const float fxl = r0.x - (float)qx0;
        const float fyl = r0.y - (float)qy0;
        float axx[4];
#pragma unroll
        for (int i = 0; i < 4; ++i)
            axx[i] = fmaxf(1.0f - fabsf(fxl - (float)i), 0.0f);

        const float fyf = floorf(fyl);
        const int   j0  = (int)fyf;        // wave-uniform, in [-1, 3]
        const float fr  = fyl - fyf;
        const float wA  = 1.0f - fr, wB = fr;
        switch (j0) {
            case -1: ROW4(0, wB); break;
            case 0:  ROW4(0, wA); ROW4(1, wB); break;
            case 1:  ROW4(1, wA); ROW4(2, wB); break;
            case 2:  ROW4(2, wA); ROW4(3, wB); break;
            default: ROW4(3, wA); break;   // j0 == 3
        }

        // fused norm
        const float axn = fmaxf(1.0f - fabsf(r0.x - Xp), 0.0f);
        const float ayn = fmaxf(1.0f - fabsf(r0.y - Yp), 0.0f);
        nrm = fmaf(r0.z, axn * ayn, nrm);

        r0 = r1; r1 = r2; r2 = r3; v0 = v1; v1 = v2;
    }

    // ---- epilogue: LDS transpose (single wave, in-order), coalesced-ish out
    const float inv = (nrm == 0.0f) ? 1.0f : (1.0f / nrm);   // per-lane = per-pixel(lane&15)

#pragma unroll
    for (int px = 0; px < 16; ++px)
        st[px][lane] = acc[px];                  // lane = channel
    asm volatile("s_waitcnt lgkmcnt(0)" ::: "memory");

    float* ob = out + (size_t)b * C * HW;
    const int pl = lane & 15;                    // pixel local (matches nrm identity)
    const int cs = lane >> 4;                    // channel sub-group 0..3
    const int ooff = (qy0 + ((pl >> 2) & 3)) * W + qx0 + (pl & 3);
#pragma unroll
    for (int it = 0; it < 16; ++it) {
        const int c = it * 4 + cs;
        ob[(size_t)c * HW + ooff] = st[pl][c] * inv;
    }
}

// ===================== MID TIER (R1 fast path) ==============================
__global__ __launch_bounds__(256) void splat_nhwc(
    const float* __restrict__ input,
    const float* __restrict__ flow,
    const float* __restrict__ metric,
    float* __restrict__ scr,
    float* __restrict__ norm)
{
    __shared__ float s_val[128][65];
    __shared__ float s_fx[128], s_fy[128], s_m[128];

    const int tid = threadIdx.x;
    const int nwg = gridDim.x;
    const int bid = blockIdx.x;
    const int swz = (bid & 7) * (nwg >> 3) + (bid >> 3);

    const int blockPix = swz * 128;
    const int b = blockPix / HW;
    const int pb = blockPix - b * HW;

    if (tid < 128) {
        const int p = pb + tid;
        const int y = p / W;
        const int x = p - y * W;
        s_fx[tid] = (float)x + flow[(b * 2 + 0) * HW + p];
        s_fy[tid] = (float)y + flow[(b * 2 + 1) * HW + p];
        s_m[tid]  = __expf(metric[b * HW + p]);
    }
    {
        const int sp = tid & 127;
        const int sc = tid >> 7;
        const float* ib = input + (size_t)b * C * HW + pb + sp;
#pragma unroll
        for (int c = 0; c < 32; ++c) {
            const int ch = 2 * c + sc;
            s_val[sp][ch] = ib[(size_t)ch * HW];
        }
    }
    __syncthreads();

    const int wave = tid >> 6;
    const int lane = tid & 63;
    float* __restrict__ sb = scr + (size_t)b * HW * 64;
    float* __restrict__ nb = norm + b * HW;

    for (int k = 0; k < 32; ++k) {
        const int j = (wave << 5) | k;
        const float fx = s_fx[j], fy = s_fy[j], m = s_m[j];
        const float v = s_val[j][lane] * m;

        const float x0f = floorf(fx), y0f = floorf(fy);
        const int x0 = (int)x0f, y0 = (int)y0f;
        const int x1 = x0 + 1,   y1 = y0 + 1;
        const float wx1 = fx - x0f, wx0 = 1.0f - wx1;
        const float wy1 = fy - y0f, wy0 = 1.0f - wy1;

        const bool vx0 = (x0 >= 0) & (x0 < W);
        const bool vx1 = (x1 >= 0) & (x1 < W);
        const bool vy0 = (y0 >= 0) & (y0 < H);
        const bool vy1 = (y1 >= 0) & (y1 < H);

        if (vx0 & vy0) {
            const float w = wx0 * wy0; const int t = y0 * W + x0;
            atomicAdd(sb + (size_t)t * 64 + lane, v * w);
            if (lane == 0) atomicAdd(nb + t, m * w);
        }
        if (vx1 & vy0) {
            const float w = wx1 * wy0; const int t = y0 * W + x1;
            atomicAdd(sb + (size_t)t * 64 + lane, v * w);
            if (lane == 0) atomicAdd(nb + t, m * w);
        }
        if (vx0 & vy1) {
            const float w = wx0 * wy1; const int t = y1 * W + x0;
            atomicAdd(sb + (size_t)t * 64 + lane, v * w);
            if (lane == 0) atomicAdd(nb + t, m * w);
        }
        if (vx1 & vy1) {
            const float w = wx1 * wy1; const int t = y1 * W + x1;
            atomicAdd(sb + (size_t)t * 64 + lane, v * w);
            if (lane == 0) atomicAdd(nb + t, m * w);
        }
    }
}

__global__ __launch_bounds__(256) void untranspose_norm(
    const float* __restrict__ scr,
    const float* __restrict__ norm,
    float* __restrict__ out)
{
    __shared__ float s_t[64][65];
    __shared__ float s_inv[64];

    const int tid = threadIdx.x;
    const int strips = HW / 64;
    const int b = blockIdx.x / strips;
    const int pblk = (blockIdx.x - b * strips) * 64;

    if (tid < 64) {
        float n = norm[b * HW + pblk + tid];
        s_inv[tid] = (n == 0.0f) ? 1.0f : (1.0f / n);
    }
    const float* sb = scr + ((size_t)b * HW + pblk) * 64;
#pragma unroll
    for (int r = 0; r < 16; ++r) {
        const int pr = r * 4 + (tid >> 6);
        const int c  = tid & 63;
        s_t[pr][c] = sb[(size_t)pr * 64 + c];
    }
    __syncthreads();

    float* ob = out + (size_t)b * C * HW + pblk;
#pragma unroll
    for (int r = 0; r < 16; ++r) {
        const int c   = r * 4 + (tid >> 6);
        const int pix = tid & 63;
        ob[(size_t)c * HW + pix] = s_t[pix][c] * s_inv[pix];
    }
}

// ===================== FALLBACK (naive) =====================================
__global__ void splat_kernel(const float* __restrict__ input,
                             const float* __restrict__ flow,
                             const float* __restrict__ metric,
                             float* __restrict__ out,
                             float* __restrict__ norm)
{
    int idx = blockIdx.x * blockDim.x + threadIdx.x;
    if (idx >= N * HW) return;
    int b = idx / HW;
    int p = idx - b * HW;
    int y = p / W;
    int x = p - y * W;

    float fx = (float)x + flow[(b * 2 + 0) * HW + p];
    float fy = (float)y + flow[(b * 2 + 1) * HW + p];
    float m  = __expf(metric[b * HW + p]);

    float x0f = floorf(fx), y0f = floorf(fy);
    int x0 = (int)x0f, y0 = (int)y0f;
    int x1 = x0 + 1,   y1 = y0 + 1;
    float wx1 = fx - x0f, wx0 = 1.0f - wx1;
    float wy1 = fy - y0f, wy0 = 1.0f - wy1;

    bool vx0 = (x0 >= 0) & (x0 < W);
    bool vx1 = (x1 >= 0) & (x1 < W);
    bool vy0 = (y0 >= 0) & (y0 < H);
    bool vy1 = (y1 >= 0) & (y1 < H);

    bool vNW = vx0 & vy0, vNE = vx1 & vy0, vSW = vx0 & vy1, vSE = vx1 & vy1;
    float wNW = wx0 * wy0, wNE = wx1 * wy0, wSW = wx0 * wy1, wSE = wx1 * wy1;
    int iNW = y0 * W + x0, iNE = y0 * W + x1, iSW = y1 * W + x0, iSE = y1 * W + x1;

    {
        float* nb = norm + b * HW;
        if (vNW) atomicAdd(nb + iNW, m * wNW);
        if (vNE) atomicAdd(nb + iNE, m * wNE);
        if (vSW) atomicAdd(nb + iSW, m * wSW);
        if (vSE) atomicAdd(nb + iSE, m * wSE);
    }

    const float* ib = input + (size_t)b * C * HW + p;
    float* ob = out + (size_t)b * C * HW;
#pragma unroll 4
    for (int c = 0; c < C; ++c) {
        float v = ib[(size_t)c * HW] * m;
        float* oc = ob + (size_t)c * HW;
        if (vNW) atomicAdd(oc + iNW, v * wNW);
        if (vNE) atomicAdd(oc + iNE, v * wNE);
        if (vSW) atomicAdd(oc + iSW, v * wSW);
        if (vSE) atomicAdd(oc + iSE, v * wSE);
    }
}

__global__ void norm_kernel(float* __restrict__ out,
                            const float* __restrict__ norm)
{
    int idx = blockIdx.x * blockDim.x + threadIdx.x;
    int total = N * C * HW / 4;
    if (idx >= total) return;

    int pixq = idx % (HW / 4);
    int bc   = idx / (HW / 4);
    int b    = bc / C;

    const float4* np4 = (const float4*)(norm + (size_t)b * HW);
    float4 n = np4[pixq];
    n.x = (n.x == 0.0f) ? 1.0f : n.x;
    n.y = (n.y == 0.0f) ? 1.0f : n.y;
    n.z = (n.z == 0.0f) ? 1.0f : n.z;
    n.w = (n.w == 0.0f) ? 1.0f : n.w;

    float4* o4 = (float4*)out;
    float4 v = o4[idx];
    v.x /= n.x; v.y /= n.y; v.z /= n.z; v.w /= n.w;
    o4[idx] = v;
}

// ============================================================================
extern "C" void kernel_launch(void* const* d_in, const int* in_sizes, int n_in,
                              void* d_out, int out_size, void* d_ws, size_t ws_size,
                              hipStream_t stream)
{
    const float* input  = (const float*)d_in[0];   // (4,64,256,448)
    const float* flow   = (const float*)d_in[1];   // (4,2,256,448)
    const float* metric = (const float*)d_in[2];   // (4,1,256,448)
    float* out = (float*)d_out;

    const size_t augBytes  = (size_t)N * HW * 64 * sizeof(float);   // 117.44 MB
    const size_t metaBytes = ((size_t)BINS * 2 + BINS + 1) * sizeof(unsigned);

    // Record-capacity tiers (16 B records). Expected usage ~1.56 * N*HW.
    const size_t capFull = (size_t)4 * N * HW;
    const size_t cap2x   = (size_t)2 * N * HW;

    auto need = [&](size_t capE) {
        return augBytes + capE * sizeof(float4) + metaBytes;
    };
    const size_t need_mid = augBytes + (size_t)N * HW * sizeof(float);

    size_t capE = 0;
    if      (ws_size >= need(capFull)) capE = capFull;
    else if (ws_size >= need(cap2x))   capE = cap2x;

    if (capE) {
        float*    aug      = (float*)d_ws;
        float4*   recs     = (float4*)((char*)d_ws + augBytes);
        unsigned* counts   = (unsigned*)(recs + capE);
        unsigned* cursor   = counts + BINS;
        unsigned* segstart = cursor + BINS;

        hipMemsetAsync(counts, 0, 2 * BINS * sizeof(unsigned), stream);
        count_kernel<<<N * HW / 1024, 1024, 0, stream>>>(flow, counts);
        scan_kernel<<<1, 1024, 0, stream>>>(counts, segstart, (unsigned)capE);
        fill2_kernel<<<N * HW / 1024, 1024, 0, stream>>>(flow, metric, segstart,
                                                         cursor, recs, (unsigned)capE);
        augT_kernel<<<N * HW / 128, 256, 0, stream>>>(input, metric, aug);
        gather6<<<BINS, 64, 0, stream>>>(recs, aug, segstart, out);
    } else if (ws_size >= need_mid) {
        float* scr  = (float*)d_ws;
        float* norm = scr + (size_t)N * HW * 64;
        hipMemsetAsync(scr, 0, need_mid, stream);

        splat_nhwc<<<N * HW / 128, 256, 0, stream>>>(input, flow, metric, scr, norm);
        untranspose_norm<<<N * (HW / 64), 256, 0, stream>>>(scr, norm, out);
    } else {
        float* norm = (float*)d_ws;
        hipMemsetAsync(out,  0, (size_t)N * C * HW * sizeof(float), stream);
        hipMemsetAsync(norm, 0, (size_t)N * HW * sizeof(float), stream);

        splat_kernel<<<(N * HW + 255) / 256, 256, 0, stream>>>(input, flow, metric, out, norm);
        int total = N * C * HW / 4;
        norm_kernel<<<(total + 255) / 256, 256, 0, stream>>>(out, norm);
    }
}

// Round 11
// 363.361 us; speedup vs baseline: 4.7688x; 1.0677x over previous
//
#include <hip/hip_runtime.h>

constexpr int N = 4;
constexpr int C = 64;
constexpr int H = 256;
constexpr int W = 448;
constexpr int HW = H * W;

// 4x4 bins (one wave owns one bin; 16 px); 4 x-adjacent bins per block.
constexpr int BSX = 4;
constexpr int BSY = 4;
constexpr int BW_ = W / BSX;           // 112
constexpr int BH_ = H / BSY;           // 64
constexpr int BINS_PB = BW_ * BH_;     // 7168 per batch
constexpr int BINS = N * BINS_PB;      // 28672
constexpr int GRPS_PB = BINS_PB / 4;   // 1792 groups (16x4 px) per batch

// ===================== GATHER PATH (R11) ====================================
// R10 post-mortem: gather6 = 127us, VALUBusy 61%, occ 62% -- model works.
// Remaining: (a) WRITE_SIZE 286MB vs 115MB ideal: 4x4 epilogue stores 16-B
// segments, HBM writes are 64-B -> 2.5x write amplification; (b) non-gather
// 261us incl. a count kernel whose 28KB LDS caps occupancy.
// R11: gather7 = 4 waves/block = 4 x-adjacent bins; main loop unchanged per
// wave; cooperative LDS epilogue writes 16-px (64-B) channel rows.
// augTC = augT + inlined count via direct global atomics (~25 RMW/addr),
// deleting the count dispatch.

__device__ __forceinline__ int binsOf(int x0, int y0, int bins[4]) {
    const int x1 = x0 + 1, y1 = y0 + 1;
    int n = 0;
    int bxA = -2, bxB = -2, byA = -2, byB = -2;
    if ((unsigned)x0 < (unsigned)W) bxA = x0 >> 2;
    if ((unsigned)x1 < (unsigned)W) { const int t = x1 >> 2; if (t != bxA) bxB = t; }
    if ((unsigned)y0 < (unsigned)H) byA = y0 >> 2;
    if ((unsigned)y1 < (unsigned)H) { const int t = y1 >> 2; if (t != byA) byB = t; }
    if (byA >= 0) {
        if (bxA >= 0) bins[n++] = byA * BW_ + bxA;
        if (bxB >= 0) bins[n++] = byA * BW_ + bxB;
    }
    if (byB >= 0) {
        if (bxA >= 0) bins[n++] = byB * BW_ + bxA;
        if (bxB >= 0) bins[n++] = byB * BW_ + bxB;
    }
    return n;
}

// scan: exclusive prefix sum of 28672 counts (= 1024*28), clamped at capE.
__global__ __launch_bounds__(1024) void scan_kernel(
    const unsigned* __restrict__ counts,
    unsigned* __restrict__ segstart,  // [BINS+1]
    unsigned capE)
{
    __shared__ unsigned lsum[1024];
    const int tid = threadIdx.x;
    constexpr int VPT = BINS / 1024;  // 28
    unsigned v[VPT];
    unsigned s = 0;
#pragma unroll
    for (int i = 0; i < VPT; ++i) { v[i] = counts[tid * VPT + i]; s += v[i]; }
    lsum[tid] = s;
    __syncthreads();
    for (int off = 1; off < 1024; off <<= 1) {
        const unsigned t = (tid >= off) ? lsum[tid - off] : 0u;
        __syncthreads();
        lsum[tid] += t;
        __syncthreads();
    }
    unsigned run = lsum[tid] - s;
#pragma unroll
    for (int i = 0; i < VPT; ++i) {
        segstart[tid * VPT + i] = run < capE ? run : capE;
        run += v[i];
    }
    if (tid == 1023) segstart[BINS] = run < capE ? run : capE;
}

// fill2: all 1024 threads active; one source each; write 16-B records
// {fx,fy,m,bitcast(p)} via direct per-bin cursor atomics (~25 RMW/addr).
__global__ __launch_bounds__(1024) void fill2_kernel(
    const float* __restrict__ flow,
    const float* __restrict__ metric,
    const unsigned* __restrict__ segstart,
    unsigned* __restrict__ cursor,    // [BINS], pre-zeroed
    float4* __restrict__ recs,        // [capE]
    unsigned capE)
{
    const int tid = threadIdx.x;
    const int idx = blockIdx.x * 1024 + tid;     // HW % 1024 == 0
    const int b = idx / HW;
    const int p = idx - b * HW;
    const int y = p / W;
    const int x = p - y * W;

    const float fx = (float)x + flow[(b * 2 + 0) * HW + p];
    const float fy = (float)y + flow[(b * 2 + 1) * HW + p];
    const float m  = __expf(metric[b * HW + p]);
    const int x0 = (int)floorf(fx), y0 = (int)floorf(fy);

    int bn[4];
    const int nb = binsOf(x0, y0, bn);
    const float4 rec = make_float4(fx, fy, m, __int_as_float(p));
    const int tb = b * BINS_PB;
    for (int i = 0; i < nb; ++i) {
        const unsigned off = atomicAdd(&cursor[tb + bn[i]], 1u);
        const unsigned slot = segstart[tb + bn[i]] + off;
        if (slot < capE) recs[slot] = rec;
    }
}

// augTC: NCHW -> NHWC transpose (premultiplied by m) + inlined bin counting
// (direct global atomics; ~25 serialized RMW per counter across the grid).
__global__ __launch_bounds__(256) void augTC_kernel(
    const float* __restrict__ input,
    const float* __restrict__ flow,
    const float* __restrict__ metric,
    float* __restrict__ aug,          // [N*HW][64]
    unsigned* __restrict__ counts)    // [BINS], pre-zeroed
{
    __shared__ float s_val[128][65];
    __shared__ float s_m[128];

    const int tid = threadIdx.x;
    const int blockPix = blockIdx.x * 128;       // HW % 128 == 0
    const int b = blockPix / HW;
    const int pb = blockPix - b * HW;

    if (tid < 128) {
        const int p = pb + tid;
        const int y = p / W;
        const int x = p - y * W;
        const float fx = (float)x + flow[(b * 2 + 0) * HW + p];
        const float fy = (float)y + flow[(b * 2 + 1) * HW + p];
        s_m[tid] = __expf(metric[b * HW + p]);

        const int x0 = (int)floorf(fx), y0 = (int)floorf(fy);
        int bn[4];
        const int nb = binsOf(x0, y0, bn);
        const int tb = b * BINS_PB;
        for (int i = 0; i < nb; ++i) atomicAdd(&counts[tb + bn[i]], 1u);
    }

    {
        const int sp = tid & 127;
        const int sc = tid >> 7;
        const float* ib = input + (size_t)b * C * HW + pb + sp;
#pragma unroll
        for (int c = 0; c < 32; ++c) {
            const int ch = 2 * c + sc;
            s_val[sp][ch] = ib[(size_t)ch * HW];
        }
    }
    __syncthreads();

    const int wv = tid >> 6, ln = tid & 63;
    float* abase = aug + ((size_t)b * HW + pb) * 64;
#pragma unroll
    for (int it = 0; it < 32; ++it) {
        const int j = (wv << 5) + it;
        abase[(size_t)j * 64 + ln] = s_val[j][ln] * s_m[j];
    }
}

// Static-index row accumulate (J must be a literal at each call site).
#define ROW4(J, WGT) do { const float tv_ = v0 * (WGT);                   \
    _Pragma("unroll")                                                     \
    for (int i_ = 0; i_ < 4; ++i_)                                        \
        acc[(J) * 4 + i_] = fmaf(tv_, axx[i_], acc[(J) * 4 + i_]);        \
} while (0)

// gather7: grid = BINS/4 blocks x 256 threads. Wave w owns bin group+w
// (4 x-adjacent 4x4 bins). Main loop identical to R10's gather6 per wave.
// Epilogue: one barrier, LDS-staged cooperative write of 16-px (64-B)
// channel rows -> write amplification 2.5x -> ~1.15x.
__global__ __launch_bounds__(256, 2) void gather7(
    const float4* __restrict__ recs,
    const float* __restrict__ aug,
    const unsigned* __restrict__ segstart,
    float* __restrict__ out)
{
    __shared__ float st[4][16][65];   // 16.6 KB (pad 65: conflict-light)
    __shared__ float s_inv[4][16];

    const int tid  = threadIdx.x;
    const int wq   = tid >> 6;
    const int lane = tid & 63;

    // XCD-contiguous swizzle (grid 7168 % 8 == 0)
    const int nwg = gridDim.x;
    const int bid = blockIdx.x;
    const int gg  = (bid & 7) * (nwg >> 3) + (bid >> 3);   // group id

    const int b    = gg / GRPS_PB;
    const int rem  = gg - b * GRPS_PB;
    const int by   = rem / (BW_ / 4);                      // 28 groups per row
    const int kx   = rem - by * (BW_ / 4);
    const int qy0  = by * BSY;
    const int qx0g = kx * 16;                              // group x origin
    const int qx0  = qx0g + wq * BSX;                      // this wave's bin
    const int g    = b * BINS_PB + by * BW_ + kx * 4 + wq; // global bin id

    // norm identity: pixel (lane&15) -> (x = lane&3, y = (lane>>2)&3).
    const float Xp = (float)(qx0 + (lane & 3));
    const float Yp = (float)(qy0 + ((lane >> 2) & 3));

    float acc[16];
#pragma unroll
    for (int i = 0; i < 16; ++i) acc[i] = 0.0f;
    float nrm = 0.0f;

    const int start = (int)segstart[g];
    const int end   = (int)segstart[g + 1];
    const float* ab = aug + (size_t)b * HW * 64;

    const float4 Z = make_float4(0.0f, 0.0f, 0.0f, __int_as_float(0));
    float4 r0 = Z, r1 = Z, r2 = Z;
    float v0 = 0.0f, v1 = 0.0f;
    if (start + 0 < end) r0 = recs[start + 0];
    if (start + 1 < end) r1 = recs[start + 1];
    if (start + 2 < end) r2 = recs[start + 2];
    if (start + 0 < end) {
        const int p0 = __builtin_amdgcn_readfirstlane(__float_as_int(r0.w));
        v0 = ab[(size_t)p0 * 64 + lane];
    }
    if (start + 1 < end) {
        const int p1 = __builtin_amdgcn_readfirstlane(__float_as_int(r1.w));
        v1 = ab[(size_t)p1 * 64 + lane];
    }

    for (int e = start; e < end; ++e) {
        // keep records 3 ahead, rows 2 ahead
        float4 r3 = Z;
        if (e + 3 < end) r3 = recs[e + 3];
        float v2 = 0.0f;
        if (e + 2 < end) {
            const int p2 = __builtin_amdgcn_readfirstlane(__float_as_int(r2.w));
            v2 = ab[(size_t)p2 * 64 + lane];
        }

        // ---- compute with r0, v0 ----
        const float fxl = r0.x - (float)qx0;
        const float fyl = r0.y - (float)qy0;
        float axx[4];
#pragma unroll
        for (int i = 0; i < 4; ++i)
            axx[i] = fmaxf(1.0f - fabsf(fxl - (float)i), 0.0f);

        const float fyf = floorf(fyl);
        const int   j0  = (int)fyf;        // wave-uniform, in [-1, 3]
        const float fr  = fyl - fyf;
        const float wA  = 1.0f - fr, wB = fr;
        switch (j0) {
            case -1: ROW4(0, wB); break;
            case 0:  ROW4(0, wA); ROW4(1, wB); break;
            case 1:  ROW4(1, wA); ROW4(2, wB); break;
            case 2:  ROW4(2, wA); ROW4(3, wB); break;
            default: ROW4(3, wA); break;   // j0 == 3
        }

        // fused norm
        const float axn = fmaxf(1.0f - fabsf(r0.x - Xp), 0.0f);
        const float ayn = fmaxf(1.0f - fabsf(r0.y - Yp), 0.0f);
        nrm = fmaf(r0.z, axn * ayn, nrm);

        r0 = r1; r1 = r2; r2 = r3; v0 = v1; v1 = v2;
    }

    // ---- cooperative epilogue: stage 4 bins in LDS, write 64-B rows ----
    const float inv = (nrm == 0.0f) ? 1.0f : (1.0f / nrm);
#pragma unroll
    for (int px = 0; px < 16; ++px)
        st[wq][px][lane] = acc[px];              // lane = channel
    if (lane < 16) s_inv[wq][lane] = inv;        // lanes 0-15 cover all 16 px
    __syncthreads();

    float* ob = out + (size_t)b * C * HW;
    const int px  = tid & 15;                    // global x within 16-px group
    const int sub = tid >> 4;                    // 0..15
    const int binl = px >> 2;                    // which bin
#pragma unroll
    for (int it = 0; it < 16; ++it) {
        const int k   = it * 16 + sub;           // 0..255 = (c, row)
        const int c   = k >> 2;
        const int row = k & 3;
        const int pl  = row * 4 + (px & 3);      // pixel within bin
        ob[(size_t)c * HW + (qy0 + row) * W + qx0g + px] =
            st[binl][pl][c] * s_inv[binl][pl];
    }
}

// ===================== MID TIER (R1 fast path) ==============================
__global__ __launch_bounds__(256) void splat_nhwc(
    const float* __restrict__ input,
    const float* __restrict__ flow,
    const float* __restrict__ metric,
    float* __restrict__ scr,
    float* __restrict__ norm)
{
    __shared__ float s_val[128][65];
    __shared__ float s_fx[128], s_fy[128], s_m[128];

    const int tid = threadIdx.x;
    const int nwg = gridDim.x;
    const int bid = blockIdx.x;
    const int swz = (bid & 7) * (nwg >> 3) + (bid >> 3);

    const int blockPix = swz * 128;
    const int b = blockPix / HW;
    const int pb = blockPix - b * HW;

    if (tid < 128) {
        const int p = pb + tid;
        const int y = p / W;
        const int x = p - y * W;
        s_fx[tid] = (float)x + flow[(b * 2 + 0) * HW + p];
        s_fy[tid] = (float)y + flow[(b * 2 + 1) * HW + p];
        s_m[tid]  = __expf(metric[b * HW + p]);
    }
    {
        const int sp = tid & 127;
        const int sc = tid >> 7;
        const float* ib = input + (size_t)b * C * HW + pb + sp;
#pragma unroll
        for (int c = 0; c < 32; ++c) {
            const int ch = 2 * c + sc;
            s_val[sp][ch] = ib[(size_t)ch * HW];
        }
    }
    __syncthreads();

    const int wave = tid >> 6;
    const int lane = tid & 63;
    float* __restrict__ sb = scr + (size_t)b * HW * 64;
    float* __restrict__ nb = norm + b * HW;

    for (int k = 0; k < 32; ++k) {
        const int j = (wave << 5) | k;
        const float fx = s_fx[j], fy = s_fy[j], m = s_m[j];
        const float v = s_val[j][lane] * m;

        const float x0f = floorf(fx), y0f = floorf(fy);
        const int x0 = (int)x0f, y0 = (int)y0f;
        const int x1 = x0 + 1,   y1 = y0 + 1;
        const float wx1 = fx - x0f, wx0 = 1.0f - wx1;
        const float wy1 = fy - y0f, wy0 = 1.0f - wy1;

        const bool vx0 = (x0 >= 0) & (x0 < W);
        const bool vx1 = (x1 >= 0) & (x1 < W);
        const bool vy0 = (y0 >= 0) & (y0 < H);
        const bool vy1 = (y1 >= 0) & (y1 < H);

        if (vx0 & vy0) {
            const float w = wx0 * wy0; const int t = y0 * W + x0;
            atomicAdd(sb + (size_t)t * 64 + lane, v * w);
            if (lane == 0) atomicAdd(nb + t, m * w);
        }
        if (vx1 & vy0) {
            const float w = wx1 * wy0; const int t = y0 * W + x1;
            atomicAdd(sb + (size_t)t * 64 + lane, v * w);
            if (lane == 0) atomicAdd(nb + t, m * w);
        }
        if (vx0 & vy1) {
            const float w = wx0 * wy1; const int t = y1 * W + x0;
            atomicAdd(sb + (size_t)t * 64 + lane, v * w);
            if (lane == 0) atomicAdd(nb + t, m * w);
        }
        if (vx1 & vy1) {
            const float w = wx1 * wy1; const int t = y1 * W + x1;
            atomicAdd(sb + (size_t)t * 64 + lane, v * w);
            if (lane == 0) atomicAdd(nb + t, m * w);
        }
    }
}

__global__ __launch_bounds__(256) void untranspose_norm(
    const float* __restrict__ scr,
    const float* __restrict__ norm,
    float* __restrict__ out)
{
    __shared__ float s_t[64][65];
    __shared__ float s_inv[64];

    const int tid = threadIdx.x;
    const int strips = HW / 64;
    const int b = blockIdx.x / strips;
    const int pblk = (blockIdx.x - b * strips) * 64;

    if (tid < 64) {
        float n = norm[b * HW + pblk + tid];
        s_inv[tid] = (n == 0.0f) ? 1.0f : (1.0f / n);
    }
    const float* sb = scr + ((size_t)b * HW + pblk) * 64;
#pragma unroll
    for (int r = 0; r < 16; ++r) {
        const int pr = r * 4 + (tid >> 6);
        const int c  = tid & 63;
        s_t[pr][c] = sb[(size_t)pr * 64 + c];
    }
    __syncthreads();

    float* ob = out + (size_t)b * C * HW + pblk;
#pragma unroll
    for (int r = 0; r < 16; ++r) {
        const int c   = r * 4 + (tid >> 6);
        const int pix = tid & 63;
        ob[(size_t)c * HW + pix] = s_t[pix][c] * s_inv[pix];
    }
}

// ===================== FALLBACK (naive) =====================================
__global__ void splat_kernel(const float* __restrict__ input,
                             const float* __restrict__ flow,
                             const float* __restrict__ metric,
                             float* __restrict__ out,
                             float* __restrict__ norm)
{
    int idx = blockIdx.x * blockDim.x + threadIdx.x;
    if (idx >= N * HW) return;
    int b = idx / HW;
    int p = idx - b * HW;
    int y = p / W;
    int x = p - y * W;

    float fx = (float)x + flow[(b * 2 + 0) * HW + p];
    float fy = (float)y + flow[(b * 2 + 1) * HW + p];
    float m  = __expf(metric[b * HW + p]);

    float x0f = floorf(fx), y0f = floorf(fy);
    int x0 = (int)x0f, y0 = (int)y0f;
    int x1 = x0 + 1,   y1 = y0 + 1;
    float wx1 = fx - x0f, wx0 = 1.0f - wx1;
    float wy1 = fy - y0f, wy0 = 1.0f - wy1;

    bool vx0 = (x0 >= 0) & (x0 < W);
    bool vx1 = (x1 >= 0) & (x1 < W);
    bool vy0 = (y0 >= 0) & (y0 < H);
    bool vy1 = (y1 >= 0) & (y1 < H);

    bool vNW = vx0 & vy0, vNE = vx1 & vy0, vSW = vx0 & vy1, vSE = vx1 & vy1;
    float wNW = wx0 * wy0, wNE = wx1 * wy0, wSW = wx0 * wy1, wSE = wx1 * wy1;
    int iNW = y0 * W + x0, iNE = y0 * W + x1, iSW = y1 * W + x0, iSE = y1 * W + x1;

    {
        float* nb = norm + b * HW;
        if (vNW) atomicAdd(nb + iNW, m * wNW);
        if (vNE) atomicAdd(nb + iNE, m * wNE);
        if (vSW) atomicAdd(nb + iSW, m * wSW);
        if (vSE) atomicAdd(nb + iSE, m * wSE);
    }

    const float* ib = input + (size_t)b * C * HW + p;
    float* ob = out + (size_t)b * C * HW;
#pragma unroll 4
    for (int c = 0; c < C; ++c) {
        float v = ib[(size_t)c * HW] * m;
        float* oc = ob + (size_t)c * HW;
        if (vNW) atomicAdd(oc + iNW, v * wNW);
        if (vNE) atomicAdd(oc + iNE, v * wNE);
        if (vSW) atomicAdd(oc + iSW, v * wSW);
        if (vSE) atomicAdd(oc + iSE, v * wSE);
    }
}

__global__ void norm_kernel(float* __restrict__ out,
                            const float* __restrict__ norm)
{
    int idx = blockIdx.x * blockDim.x + threadIdx.x;
    int total = N * C * HW / 4;
    if (idx >= total) return;

    int pixq = idx % (HW / 4);
    int bc   = idx / (HW / 4);
    int b    = bc / C;

    const float4* np4 = (const float4*)(norm + (size_t)b * HW);
    float4 n = np4[pixq];
    n.x = (n.x == 0.0f) ? 1.0f : n.x;
    n.y = (n.y == 0.0f) ? 1.0f : n.y;
    n.z = (n.z == 0.0f) ? 1.0f : n.z;
    n.w = (n.w == 0.0f) ? 1.0f : n.w;

    float4* o4 = (float4*)out;
    float4 v = o4[idx];
    v.x /= n.x; v.y /= n.y; v.z /= n.z; v.w /= n.w;
    o4[idx] = v;
}

// ============================================================================
extern "C" void kernel_launch(void* const* d_in, const int* in_sizes, int n_in,
                              void* d_out, int out_size, void* d_ws, size_t ws_size,
                              hipStream_t stream)
{
    const float* input  = (const float*)d_in[0];   // (4,64,256,448)
    const float* flow   = (const float*)d_in[1];   // (4,2,256,448)
    const float* metric = (const float*)d_in[2];   // (4,1,256,448)
    float* out = (float*)d_out;

    const size_t augBytes  = (size_t)N * HW * 64 * sizeof(float);   // 117.44 MB
    const size_t metaBytes = ((size_t)BINS * 2 + BINS + 1) * sizeof(unsigned);

    // Record-capacity tiers (16 B records). Expected usage ~1.56 * N*HW.
    const size_t capFull = (size_t)4 * N * HW;
    const size_t cap2x   = (size_t)2 * N * HW;

    auto need = [&](size_t capE) {
        return augBytes + capE * sizeof(float4) + metaBytes;
    };
    const size_t need_mid = augBytes + (size_t)N * HW * sizeof(float);

    size_t capE = 0;
    if      (ws_size >= need(capFull)) capE = capFull;
    else if (ws_size >= need(cap2x))   capE = cap2x;

    if (capE) {
        float*    aug      = (float*)d_ws;
        float4*   recs     = (float4*)((char*)d_ws + augBytes);
        unsigned* counts   = (unsigned*)(recs + capE);
        unsigned* cursor   = counts + BINS;
        unsigned* segstart = cursor + BINS;

        hipMemsetAsync(counts, 0, 2 * BINS * sizeof(unsigned), stream);
        augTC_kernel<<<N * HW / 128, 256, 0, stream>>>(input, flow, metric,
                                                       aug, counts);
        scan_kernel<<<1, 1024, 0, stream>>>(counts, segstart, (unsigned)capE);
        fill2_kernel<<<N * HW / 1024, 1024, 0, stream>>>(flow, metric, segstart,
                                                         cursor, recs, (unsigned)capE);
        gather7<<<BINS / 4, 256, 0, stream>>>(recs, aug, segstart, out);
    } else if (ws_size >= need_mid) {
        float* scr  = (float*)d_ws;
        float* norm = scr + (size_t)N * HW * 64;
        hipMemsetAsync(scr, 0, need_mid, stream);

        splat_nhwc<<<N * HW / 128, 256, 0, stream>>>(input, flow, metric, scr, norm);
        untranspose_norm<<<N * (HW / 64), 256, 0, stream>>>(scr, norm, out);
    } else {
        float* norm = (float*)d_ws;
        hipMemsetAsync(out,  0, (size_t)N * C * HW * sizeof(float), stream);
        hipMemsetAsync(norm, 0, (size_t)N * HW * sizeof(float), stream);

        splat_kernel<<<(N * HW + 255) / 256, 256, 0, stream>>>(input, flow, metric, out, norm);
        int total = N * C * HW / 4;
        norm_kernel<<<(total + 255) / 256, 256, 0, stream>>>(out, norm);
    }
}

// Round 12
// 356.155 us; speedup vs baseline: 4.8653x; 1.0202x over previous
//
#include <hip/hip_runtime.h>

constexpr int N = 4;
constexpr int C = 64;
constexpr int H = 256;
constexpr int W = 448;
constexpr int HW = H * W;

// 4x4 bins (one wave owns one bin; 16 px); 4 x-adjacent bins per block.
constexpr int BSX = 4;
constexpr int BSY = 4;
constexpr int BW_ = W / BSX;           // 112
constexpr int BH_ = H / BSY;           // 64
constexpr int BINS_PB = BW_ * BH_;     // 7168 per batch
constexpr int BINS = N * BINS_PB;      // 28672
constexpr int GRPS_PB = BINS_PB / 4;   // 1792 groups (16x4 px) per batch

// ===================== GATHER PATH (R12) ====================================
// R11 post-mortem: write-amp fixed (286->123MB) but gather7 only 127->121us:
// VALUBusy 93.5% -> purely issue-bound, as the falsification branch said.
// Non-gather = 242us vs ~70us ideal-BW (scalar augTC copies, 1-block
// 20-barrier scan, gaps).
// R12: instruction diet. gather8 = clamped-index prefetch (no guards) +
// unroll 2 (halve rotation movs). augTC2 = float4 both directions (4x fewer
// copy instrs). scan2 = shuffle scan, 2 barriers.

__device__ __forceinline__ int binsOf(int x0, int y0, int bins[4]) {
    const int x1 = x0 + 1, y1 = y0 + 1;
    int n = 0;
    int bxA = -2, bxB = -2, byA = -2, byB = -2;
    if ((unsigned)x0 < (unsigned)W) bxA = x0 >> 2;
    if ((unsigned)x1 < (unsigned)W) { const int t = x1 >> 2; if (t != bxA) bxB = t; }
    if ((unsigned)y0 < (unsigned)H) byA = y0 >> 2;
    if ((unsigned)y1 < (unsigned)H) { const int t = y1 >> 2; if (t != byA) byB = t; }
    if (byA >= 0) {
        if (bxA >= 0) bins[n++] = byA * BW_ + bxA;
        if (bxB >= 0) bins[n++] = byA * BW_ + bxB;
    }
    if (byB >= 0) {
        if (bxA >= 0) bins[n++] = byB * BW_ + bxA;
        if (bxB >= 0) bins[n++] = byB * BW_ + bxB;
    }
    return n;
}

// scan2: exclusive prefix sum of 28672 counts, shuffle-based (2 barriers).
__global__ __launch_bounds__(1024) void scan_kernel(
    const unsigned* __restrict__ counts,
    unsigned* __restrict__ segstart,  // [BINS+1]
    unsigned capE)
{
    __shared__ unsigned wsum[16];
    const int tid = threadIdx.x;
    const int wv  = tid >> 6;
    const int ln  = tid & 63;
    constexpr int VPT = BINS / 1024;  // 28
    unsigned v[VPT];
    unsigned s = 0;
#pragma unroll
    for (int i = 0; i < VPT; ++i) { v[i] = counts[tid * VPT + i]; s += v[i]; }

    // wave-inclusive scan of per-thread sums
    unsigned incl = s;
#pragma unroll
    for (int off = 1; off < 64; off <<= 1) {
        const unsigned t = __shfl_up(incl, off);
        if (ln >= off) incl += t;
    }
    if (ln == 63) wsum[wv] = incl;
    __syncthreads();
    if (tid == 0) {
        unsigned run = 0;
#pragma unroll
        for (int i = 0; i < 16; ++i) { const unsigned t = wsum[i]; wsum[i] = run; run += t; }
    }
    __syncthreads();

    unsigned run = wsum[wv] + (incl - s);
#pragma unroll
    for (int i = 0; i < VPT; ++i) {
        segstart[tid * VPT + i] = run < capE ? run : capE;
        run += v[i];
    }
    if (tid == 1023) segstart[BINS] = run < capE ? run : capE;
}

// fill2: all 1024 threads active; one source each; write 16-B records
// {fx,fy,m,bitcast(p)} via direct per-bin cursor atomics (~25 RMW/addr).
__global__ __launch_bounds__(1024) void fill2_kernel(
    const float* __restrict__ flow,
    const float* __restrict__ metric,
    const unsigned* __restrict__ segstart,
    unsigned* __restrict__ cursor,    // [BINS], pre-zeroed
    float4* __restrict__ recs,        // [capE]
    unsigned capE)
{
    const int tid = threadIdx.x;
    const int idx = blockIdx.x * 1024 + tid;     // HW % 1024 == 0
    const int b = idx / HW;
    const int p = idx - b * HW;
    const int y = p / W;
    const int x = p - y * W;

    const float fx = (float)x + flow[(b * 2 + 0) * HW + p];
    const float fy = (float)y + flow[(b * 2 + 1) * HW + p];
    const float m  = __expf(metric[b * HW + p]);
    const int x0 = (int)floorf(fx), y0 = (int)floorf(fy);

    int bn[4];
    const int nb = binsOf(x0, y0, bn);
    const float4 rec = make_float4(fx, fy, m, __int_as_float(p));
    const int tb = b * BINS_PB;
    for (int i = 0; i < nb; ++i) {
        const unsigned off = atomicAdd(&cursor[tb + bn[i]], 1u);
        const unsigned slot = segstart[tb + bn[i]] + off;
        if (slot < capE) recs[slot] = rec;
    }
}

// augTC2: NCHW -> NHWC transpose (premultiplied by m) + inlined bin counting.
// float4 loads (4px/lane, 8ch/iter) and float4 stores (b128 LDS reads,
// 16-lane groups per pixel) -> ~4x fewer copy instructions than scalar.
__global__ __launch_bounds__(256) void augTC_kernel(
    const float* __restrict__ input,
    const float* __restrict__ flow,
    const float* __restrict__ metric,
    float* __restrict__ aug,          // [N*HW][64]
    unsigned* __restrict__ counts)    // [BINS], pre-zeroed
{
    __shared__ float s_val[128][65];
    __shared__ float s_m[128];

    const int tid = threadIdx.x;
    const int blockPix = blockIdx.x * 128;       // HW % 128 == 0
    const int b = blockPix / HW;
    const int pb = blockPix - b * HW;

    if (tid < 128) {
        const int p = pb + tid;
        const int y = p / W;
        const int x = p - y * W;
        const float fx = (float)x + flow[(b * 2 + 0) * HW + p];
        const float fy = (float)y + flow[(b * 2 + 1) * HW + p];
        s_m[tid] = __expf(metric[b * HW + p]);

        const int x0 = (int)floorf(fx), y0 = (int)floorf(fy);
        int bn[4];
        const int nb = binsOf(x0, y0, bn);
        const int tb = b * BINS_PB;
        for (int i = 0; i < nb; ++i) atomicAdd(&counts[tb + bn[i]], 1u);
    }

    // load: float4 = 4 px per lane; 8 channels per iteration (32 lanes/ch).
    {
        const int pq = 4 * (tid & 31);           // pixel quad base
        const int cs = tid >> 5;                 // 0..7
        const float* ib = input + (size_t)b * C * HW + pb + pq;
#pragma unroll
        for (int it = 0; it < 8; ++it) {
            const int ch = 8 * it + cs;
            const float4 f = *(const float4*)&ib[(size_t)ch * HW];
            s_val[pq + 0][ch] = f.x;
            s_val[pq + 1][ch] = f.y;
            s_val[pq + 2][ch] = f.z;
            s_val[pq + 3][ch] = f.w;
        }
    }
    __syncthreads();

    // store: 16-lane groups; each lane writes float4 of channels for one px.
    {
        const int wv  = tid >> 6;
        const int ln  = tid & 63;
        const int pxo = ln >> 4;                 // 0..3 within quad
        const int cb  = 4 * (ln & 15);           // channel base
        float* abase = aug + ((size_t)b * HW + pb) * 64;
#pragma unroll
        for (int it = 0; it < 8; ++it) {
            const int px = wv * 32 + it * 4 + pxo;
            const float mm = s_m[px];
            float4 v;
            v.x = s_val[px][cb + 0] * mm;
            v.y = s_val[px][cb + 1] * mm;
            v.z = s_val[px][cb + 2] * mm;
            v.w = s_val[px][cb + 3] * mm;
            *(float4*)&abase[(size_t)px * 64 + cb] = v;
        }
    }
}

// Static-index row accumulate (J must be a literal at each call site).
#define ROW4(J, WGT) do { const float tv_ = v0 * (WGT);                   \
    _Pragma("unroll")                                                     \
    for (int i_ = 0; i_ < 4; ++i_)                                        \
        acc[(J) * 4 + i_] = fmaf(tv_, axx[i_], acc[(J) * 4 + i_]);        \
} while (0)

// gather8: grid = BINS/4 blocks x 256 threads. Wave w owns bin group+w.
// Clamped-index prefetch (no per-iteration guards; duplicated prefetches
// are never consumed), unroll 2. Cooperative 64-B epilogue unchanged.
__global__ __launch_bounds__(256, 2) void gather8(
    const float4* __restrict__ recs,
    const float* __restrict__ aug,
    const unsigned* __restrict__ segstart,
    float* __restrict__ out)
{
    __shared__ float st[4][16][65];   // 16.6 KB
    __shared__ float s_inv[4][16];

    const int tid  = threadIdx.x;
    const int wq   = tid >> 6;
    const int lane = tid & 63;

    // XCD-contiguous swizzle (grid 7168 % 8 == 0)
    const int nwg = gridDim.x;
    const int bid = blockIdx.x;
    const int gg  = (bid & 7) * (nwg >> 3) + (bid >> 3);   // group id

    const int b    = gg / GRPS_PB;
    const int rem  = gg - b * GRPS_PB;
    const int by   = rem / (BW_ / 4);                      // 28 groups per row
    const int kx   = rem - by * (BW_ / 4);
    const int qy0  = by * BSY;
    const int qx0g = kx * 16;                              // group x origin
    const int qx0  = qx0g + wq * BSX;                      // this wave's bin
    const int g    = b * BINS_PB + by * BW_ + kx * 4 + wq; // global bin id

    const float Xp = (float)(qx0 + (lane & 3));
    const float Yp = (float)(qy0 + ((lane >> 2) & 3));

    float acc[16];
#pragma unroll
    for (int i = 0; i < 16; ++i) acc[i] = 0.0f;
    float nrm = 0.0f;

    const int start = (int)segstart[g];
    const int end   = (int)segstart[g + 1];
    const float* ab = aug + (size_t)b * HW * 64;

    if (start < end) {
        const int last = end - 1;
        float4 r0 = recs[start];
        float4 r1 = recs[min(start + 1, last)];
        float4 r2 = recs[min(start + 2, last)];
        const int p0 = __builtin_amdgcn_readfirstlane(__float_as_int(r0.w));
        float v0 = ab[(size_t)p0 * 64 + lane];
        const int p1 = __builtin_amdgcn_readfirstlane(__float_as_int(r1.w));
        float v1 = ab[(size_t)p1 * 64 + lane];

#pragma unroll 2
        for (int e = start; e < end; ++e) {
            // clamped prefetch: records 3 ahead, rows 2 ahead (no guards)
            const float4 r3 = recs[min(e + 3, last)];
            const int p2 = __builtin_amdgcn_readfirstlane(__float_as_int(r2.w));
            const float v2 = ab[(size_t)p2 * 64 + lane];

            // ---- compute with r0, v0 ----
            const float fxl = r0.x - (float)qx0;
            const float fyl = r0.y - (float)qy0;
            float axx[4];
#pragma unroll
            for (int i = 0; i < 4; ++i)
                axx[i] = fmaxf(1.0f - fabsf(fxl - (float)i), 0.0f);

            const float fyf = floorf(fyl);
            const int   j0  = (int)fyf;        // wave-uniform, in [-1, 3]
            const float fr  = fyl - fyf;
            const float wA  = 1.0f - fr, wB = fr;
            switch (j0) {
                case -1: ROW4(0, wB); break;
                case 0:  ROW4(0, wA); ROW4(1, wB); break;
                case 1:  ROW4(1, wA); ROW4(2, wB); break;
                case 2:  ROW4(2, wA); ROW4(3, wB); break;
                default: ROW4(3, wA); break;   // j0 == 3
            }

            // fused norm
            const float axn = fmaxf(1.0f - fabsf(r0.x - Xp), 0.0f);
            const float ayn = fmaxf(1.0f - fabsf(r0.y - Yp), 0.0f);
            nrm = fmaf(r0.z, axn * ayn, nrm);

            r0 = r1; r1 = r2; r2 = r3; v0 = v1; v1 = v2;
        }
    }

    // ---- cooperative epilogue: stage 4 bins in LDS, write 64-B rows ----
    const float inv = (nrm == 0.0f) ? 1.0f : (1.0f / nrm);
#pragma unroll
    for (int px = 0; px < 16; ++px)
        st[wq][px][lane] = acc[px];              // lane = channel
    if (lane < 16) s_inv[wq][lane] = inv;        // lanes 0-15 cover all 16 px
    __syncthreads();

    float* ob = out + (size_t)b * C * HW;
    const int px  = tid & 15;                    // global x within 16-px group
    const int sub = tid >> 4;                    // 0..15
    const int binl = px >> 2;                    // which bin
#pragma unroll
    for (int it = 0; it < 16; ++it) {
        const int k   = it * 16 + sub;           // 0..255 = (c, row)
        const int c   = k >> 2;
        const int row = k & 3;
        const int pl  = row * 4 + (px & 3);      // pixel within bin
        ob[(size_t)c * HW + (qy0 + row) * W + qx0g + px] =
            st[binl][pl][c] * s_inv[binl][pl];
    }
}

// ===================== MID TIER (R1 fast path) ==============================
__global__ __launch_bounds__(256) void splat_nhwc(
    const float* __restrict__ input,
    const float* __restrict__ flow,
    const float* __restrict__ metric,
    float* __restrict__ scr,
    float* __restrict__ norm)
{
    __shared__ float s_val[128][65];
    __shared__ float s_fx[128], s_fy[128], s_m[128];

    const int tid = threadIdx.x;
    const int nwg = gridDim.x;
    const int bid = blockIdx.x;
    const int swz = (bid & 7) * (nwg >> 3) + (bid >> 3);

    const int blockPix = swz * 128;
    const int b = blockPix / HW;
    const int pb = blockPix - b * HW;

    if (tid < 128) {
        const int p = pb + tid;
        const int y = p / W;
        const int x = p - y * W;
        s_fx[tid] = (float)x + flow[(b * 2 + 0) * HW + p];
        s_fy[tid] = (float)y + flow[(b * 2 + 1) * HW + p];
        s_m[tid]  = __expf(metric[b * HW + p]);
    }
    {
        const int sp = tid & 127;
        const int sc = tid >> 7;
        const float* ib = input + (size_t)b * C * HW + pb + sp;
#pragma unroll
        for (int c = 0; c < 32; ++c) {
            const int ch = 2 * c + sc;
            s_val[sp][ch] = ib[(size_t)ch * HW];
        }
    }
    __syncthreads();

    const int wave = tid >> 6;
    const int lane = tid & 63;
    float* __restrict__ sb = scr + (size_t)b * HW * 64;
    float* __restrict__ nb = norm + b * HW;

    for (int k = 0; k < 32; ++k) {
        const int j = (wave << 5) | k;
        const float fx = s_fx[j], fy = s_fy[j], m = s_m[j];
        const float v = s_val[j][lane] * m;

        const float x0f = floorf(fx), y0f = floorf(fy);
        const int x0 = (int)x0f, y0 = (int)y0f;
        const int x1 = x0 + 1,   y1 = y0 + 1;
        const float wx1 = fx - x0f, wx0 = 1.0f - wx1;
        const float wy1 = fy - y0f, wy0 = 1.0f - wy1;

        const bool vx0 = (x0 >= 0) & (x0 < W);
        const bool vx1 = (x1 >= 0) & (x1 < W);
        const bool vy0 = (y0 >= 0) & (y0 < H);
        const bool vy1 = (y1 >= 0) & (y1 < H);

        if (vx0 & vy0) {
            const float w = wx0 * wy0; const int t = y0 * W + x0;
            atomicAdd(sb + (size_t)t * 64 + lane, v * w);
            if (lane == 0) atomicAdd(nb + t, m * w);
        }
        if (vx1 & vy0) {
            const float w = wx1 * wy0; const int t = y0 * W + x1;
            atomicAdd(sb + (size_t)t * 64 + lane, v * w);
            if (lane == 0) atomicAdd(nb + t, m * w);
        }
        if (vx0 & vy1) {
            const float w = wx0 * wy1; const int t = y1 * W + x0;
            atomicAdd(sb + (size_t)t * 64 + lane, v * w);
            if (lane == 0) atomicAdd(nb + t, m * w);
        }
        if (vx1 & vy1) {
            const float w = wx1 * wy1; const int t = y1 * W + x1;
            atomicAdd(sb + (size_t)t * 64 + lane, v * w);
            if (lane == 0) atomicAdd(nb + t, m * w);
        }
    }
}

__global__ __launch_bounds__(256) void untranspose_norm(
    const float* __restrict__ scr,
    const float* __restrict__ norm,
    float* __restrict__ out)
{
    __shared__ float s_t[64][65];
    __shared__ float s_inv[64];

    const int tid = threadIdx.x;
    const int strips = HW / 64;
    const int b = blockIdx.x / strips;
    const int pblk = (blockIdx.x - b * strips) * 64;

    if (tid < 64) {
        float n = norm[b * HW + pblk + tid];
        s_inv[tid] = (n == 0.0f) ? 1.0f : (1.0f / n);
    }
    const float* sb = scr + ((size_t)b * HW + pblk) * 64;
#pragma unroll
    for (int r = 0; r < 16; ++r) {
        const int pr = r * 4 + (tid >> 6);
        const int c  = tid & 63;
        s_t[pr][c] = sb[(size_t)pr * 64 + c];
    }
    __syncthreads();

    float* ob = out + (size_t)b * C * HW + pblk;
#pragma unroll
    for (int r = 0; r < 16; ++r) {
        const int c   = r * 4 + (tid >> 6);
        const int pix = tid & 63;
        ob[(size_t)c * HW + pix] = s_t[pix][c] * s_inv[pix];
    }
}

// ===================== FALLBACK (naive) =====================================
__global__ void splat_kernel(const float* __restrict__ input,
                             const float* __restrict__ flow,
                             const float* __restrict__ metric,
                             float* __restrict__ out,
                             float* __restrict__ norm)
{
    int idx = blockIdx.x * blockDim.x + threadIdx.x;
    if (idx >= N * HW) return;
    int b = idx / HW;
    int p = idx - b * HW;
    int y = p / W;
    int x = p - y * W;

    float fx = (float)x + flow[(b * 2 + 0) * HW + p];
    float fy = (float)y + flow[(b * 2 + 1) * HW + p];
    float m  = __expf(metric[b * HW + p]);

    float x0f = floorf(fx), y0f = floorf(fy);
    int x0 = (int)x0f, y0 = (int)y0f;
    int x1 = x0 + 1,   y1 = y0 + 1;
    float wx1 = fx - x0f, wx0 = 1.0f - wx1;
    float wy1 = fy - y0f, wy0 = 1.0f - wy1;

    bool vx0 = (x0 >= 0) & (x0 < W);
    bool vx1 = (x1 >= 0) & (x1 < W);
    bool vy0 = (y0 >= 0) & (y0 < H);
    bool vy1 = (y1 >= 0) & (y1 < H);

    bool vNW = vx0 & vy0, vNE = vx1 & vy0, vSW = vx0 & vy1, vSE = vx1 & vy1;
    float wNW = wx0 * wy0, wNE = wx1 * wy0, wSW = wx0 * wy1, wSE = wx1 * wy1;
    int iNW = y0 * W + x0, iNE = y0 * W + x1, iSW = y1 * W + x0, iSE = y1 * W + x1;

    {
        float* nb = norm + b * HW;
        if (vNW) atomicAdd(nb + iNW, m * wNW);
        if (vNE) atomicAdd(nb + iNE, m * wNE);
        if (vSW) atomicAdd(nb + iSW, m * wSW);
        if (vSE) atomicAdd(nb + iSE, m * wSE);
    }

    const float* ib = input + (size_t)b * C * HW + p;
    float* ob = out + (size_t)b * C * HW;
#pragma unroll 4
    for (int c = 0; c < C; ++c) {
        float v = ib[(size_t)c * HW] * m;
        float* oc = ob + (size_t)c * HW;
        if (vNW) atomicAdd(oc + iNW, v * wNW);
        if (vNE) atomicAdd(oc + iNE, v * wNE);
        if (vSW) atomicAdd(oc + iSW, v * wSW);
        if (vSE) atomicAdd(oc + iSE, v * wSE);
    }
}

__global__ void norm_kernel(float* __restrict__ out,
                            const float* __restrict__ norm)
{
    int idx = blockIdx.x * blockDim.x + threadIdx.x;
    int total = N * C * HW / 4;
    if (idx >= total) return;

    int pixq = idx % (HW / 4);
    int bc   = idx / (HW / 4);
    int b    = bc / C;

    const float4* np4 = (const float4*)(norm + (size_t)b * HW);
    float4 n = np4[pixq];
    n.x = (n.x == 0.0f) ? 1.0f : n.x;
    n.y = (n.y == 0.0f) ? 1.0f : n.y;
    n.z = (n.z == 0.0f) ? 1.0f : n.z;
    n.w = (n.w == 0.0f) ? 1.0f : n.w;

    float4* o4 = (float4*)out;
    float4 v = o4[idx];
    v.x /= n.x; v.y /= n.y; v.z /= n.z; v.w /= n.w;
    o4[idx] = v;
}

// ============================================================================
extern "C" void kernel_launch(void* const* d_in, const int* in_sizes, int n_in,
                              void* d_out, int out_size, void* d_ws, size_t ws_size,
                              hipStream_t stream)
{
    const float* input  = (const float*)d_in[0];   // (4,64,256,448)
    const float* flow   = (const float*)d_in[1];   // (4,2,256,448)
    const float* metric = (const float*)d_in[2];   // (4,1,256,448)
    float* out = (float*)d_out;

    const size_t augBytes  = (size_t)N * HW * 64 * sizeof(float);   // 117.44 MB
    const size_t metaBytes = ((size_t)BINS * 2 + BINS + 1) * sizeof(unsigned);

    // Record-capacity tiers (16 B records). Expected usage ~1.56 * N*HW.
    const size_t capFull = (size_t)4 * N * HW;
    const size_t cap2x   = (size_t)2 * N * HW;

    auto need = [&](size_t capE) {
        return augBytes + capE * sizeof(float4) + metaBytes;
    };
    const size_t need_mid = augBytes + (size_t)N * HW * sizeof(float);

    size_t capE = 0;
    if      (ws_size >= need(capFull)) capE = capFull;
    else if (ws_size >= need(cap2x))   capE = cap2x;

    if (capE) {
        float*    aug      = (float*)d_ws;
        float4*   recs     = (float4*)((char*)d_ws + augBytes);
        unsigned* counts   = (unsigned*)(recs + capE);
        unsigned* cursor   = counts + BINS;
        unsigned* segstart = cursor + BINS;

        hipMemsetAsync(counts, 0, 2 * BINS * sizeof(unsigned), stream);
        augTC_kernel<<<N * HW / 128, 256, 0, stream>>>(input, flow, metric,
                                                       aug, counts);
        scan_kernel<<<1, 1024, 0, stream>>>(counts, segstart, (unsigned)capE);
        fill2_kernel<<<N * HW / 1024, 1024, 0, stream>>>(flow, metric, segstart,
                                                         cursor, recs, (unsigned)capE);
        gather8<<<BINS / 4, 256, 0, stream>>>(recs, aug, segstart, out);
    } else if (ws_size >= need_mid) {
        float* scr  = (float*)d_ws;
        float* norm = scr + (size_t)N * HW * 64;
        hipMemsetAsync(scr, 0, need_mid, stream);

        splat_nhwc<<<N * HW / 128, 256, 0, stream>>>(input, flow, metric, scr, norm);
        untranspose_norm<<<N * (HW / 64), 256, 0, stream>>>(scr, norm, out);
    } else {
        float* norm = (float*)d_ws;
        hipMemsetAsync(out,  0, (size_t)N * C * HW * sizeof(float), stream);
        hipMemsetAsync(norm, 0, (size_t)N * HW * sizeof(float), stream);

        splat_kernel<<<(N * HW + 255) / 256, 256, 0, stream>>>(input, flow, metric, out, norm);
        int total = N * C * HW / 4;
        norm_kernel<<<(total + 255) / 256, 256, 0, stream>>>(out, norm);
    }
}